// Round 3
// baseline (359.586 us; speedup 1.0000x reference)
//
#include <hip/hip_runtime.h>
#include <math.h>

#define TPB 256

// ---------------- layer geometry ----------------
constexpr int DIMS_[5]  = {480, 240, 120, 60, 30};
constexpr int CHS_ [5]  = {64, 128, 256, 512, 512};
constexpr int CHB_ [5]  = {0, 64, 192, 448, 960};
constexpr int TOTCH     = 1472;
constexpr int PROCB_[5] = {0, 230400, 288000, 302400, 306000};
constexpr int PROCTOT   = 306900;

// ---------------- ws layout (4-byte words) ----------------
constexpr int O_CHMIN = 0;                  // f32 [1472]  (UNUSED: min==0 by construction)
constexpr int O_CHMAX = 1472;               // f32 [1472]
constexpr int O_HIST  = 2944;               // u32 [1472*6]: slots 0..4 = raw count(v>=th[k])
constexpr int O_GCNT  = 11776;              // u32 [1472*6]: slots 0..4 = raw count(v>=tg[k])
constexpr int O_CLUT  = 20608;              // f32 [1472*16]: gthr[0..4], pad, lut[8..13]
constexpr int O_BSUM  = O_CLUT + 16 * 1472; // 44160: f32 [5]
constexpr int O_PMIN  = O_BSUM + 5;         // u32 [5]
constexpr int O_PMAX  = O_PMIN + 5;         // u32 [5]
constexpr int O_S3MIN = O_PMAX + 5;         // u32 [5]
constexpr int O_S3MAX = O_S3MIN + 5;        // u32 [5]
constexpr int O_S3SUM = O_S3MAX + 5;        // f32 [5]
constexpr int O_PROC  = 44192;              // f32 [306900] (zero-init; chunked layers atomicAdd)
constexpr int O_RESZ  = O_PROC + PROCTOT;   // f32 [5*57600]
constexpr int N_INIT  = O_PROC + PROCTOT;   // init range

struct P {
  const float* in[5];
  float* ws;
};

// ---------------- threshold helpers (array form: kS only) ----------------
__device__ __forceinline__ void mk_hthr(float mn, float rng, float* th) {
  if (rng == 0.0f) { th[0]=th[1]=th[2]=th[3]=th[4]=INFINITY; return; }
  th[0] = mn + rng * (1.0f / 6.0f); th[1] = mn + rng * (2.0f / 6.0f);
  th[2] = mn + rng * (3.0f / 6.0f); th[3] = mn + rng * (4.0f / 6.0f);
  th[4] = mn + rng * (5.0f / 6.0f);
}
__device__ __forceinline__ void mk_gthr(float mn, float rng, float* tg) {
  if (rng == 0.0f) { tg[0]=tg[1]=tg[2]=tg[3]=tg[4]=INFINITY; return; }
  tg[0] = mn + rng * (2.0f / 1536.0f); tg[1] = mn + rng * (3.0f / 1536.0f);
  tg[2] = mn + rng * (4.0f / 1536.0f); tg[3] = mn + rng * (5.0f / 1536.0f);
  tg[4] = mn + rng * (6.0f / 1536.0f);
}

// scalar threshold block (mn == 0): defines th0..th4, tg0..tg4 from rng
#define MK_THR_SCALAR(rng)                                                          \
  float th0, th1, th2, th3, th4, tg0, tg1, tg2, tg3, tg4;                           \
  if ((rng) == 0.0f) {                                                              \
    th0=th1=th2=th3=th4=tg0=tg1=tg2=tg3=tg4=INFINITY;                               \
  } else {                                                                          \
    th0 = (rng) * (1.0f/6.0f);    th1 = (rng) * (2.0f/6.0f);                        \
    th2 = (rng) * (3.0f/6.0f);    th3 = (rng) * (4.0f/6.0f);                        \
    th4 = (rng) * (5.0f/6.0f);                                                      \
    tg0 = (rng) * (2.0f/1536.0f); tg1 = (rng) * (3.0f/1536.0f);                     \
    tg2 = (rng) * (4.0f/1536.0f); tg3 = (rng) * (5.0f/1536.0f);                     \
    tg4 = (rng) * (6.0f/1536.0f);                                                   \
  }

// per-element raw compare-count update (pure VALU: v_cmp + v_addc)
#define CNT1(x) do {                                                                \
  h0 += ((x) >= th0); h1 += ((x) >= th1); h2 += ((x) >= th2);                       \
  h3 += ((x) >= th3); h4 += ((x) >= th4);                                           \
  g0 += ((x) >= tg0); g1 += ((x) >= tg1); g2 += ((x) >= tg2);                       \
  g3 += ((x) >= tg3); g4 += ((x) >= tg4); } while (0)

// wave-64 sum / max reductions on a named scalar
#define WREDS(v) do { v += __shfl_down(v,32); v += __shfl_down(v,16);               \
  v += __shfl_down(v,8); v += __shfl_down(v,4); v += __shfl_down(v,2);              \
  v += __shfl_down(v,1); } while (0)
#define WREDM(v) do { v = fmaxf(v, __shfl_down(v,32)); v = fmaxf(v, __shfl_down(v,16)); \
  v = fmaxf(v, __shfl_down(v,8)); v = fmaxf(v, __shfl_down(v,4));                   \
  v = fmaxf(v, __shfl_down(v,2)); v = fmaxf(v, __shfl_down(v,1)); } while (0)

// clamped load (always issued, in-bounds; compute is guarded separately)
#define LDC(nm, ii) float4 nm = pv[(ii) * TPB + t <= last ? (ii) * TPB + t : last]

// ---------------- init ----------------
__global__ void k_init(float* ws) {
  int i = blockIdx.x * TPB + threadIdx.x;
  if (i >= N_INIT) return;
  unsigned v = 0u;
  if (i >= O_PMIN  && i < O_PMAX)  v = 0x7F800000u;  // pmin = +inf
  else if (i >= O_S3MIN && i < O_S3MAX) v = 0x7F800000u;  // s3min
  ((unsigned*)ws)[i] = v;
}

// ---------------- pass A: per-channel MAX of border-zeroed map ----------------
// min == 0 always (borders are zeroed, inputs nonneg), so max-only.
// 16 clamped loads issued straight-line -> 16 loads in flight per wave.
template <int D>
__device__ __forceinline__ float zbmax4(float4 v, int f4i) {
  if constexpr (D % 4 == 0) {
    constexpr int DQ = D / 4;
    int y = f4i / DQ, xq = f4i - y * DQ;
    if (y == 0 || y == D - 1) return 0.0f;
    if (xq == 0)      v.x = 0.0f;
    if (xq == DQ - 1) v.w = 0.0f;
    return fmaxf(fmaxf(v.x, v.y), fmaxf(v.z, v.w));
  } else {
    int e0 = f4i * 4;
    float m = 0.0f;
    { int e = e0,     y = e / D, x = e - y * D;
      if (((unsigned)(x-1) < (unsigned)(D-2)) && ((unsigned)(y-1) < (unsigned)(D-2))) m = fmaxf(m, v.x); }
    { int e = e0 + 1, y = e / D, x = e - y * D;
      if (((unsigned)(x-1) < (unsigned)(D-2)) && ((unsigned)(y-1) < (unsigned)(D-2))) m = fmaxf(m, v.y); }
    { int e = e0 + 2, y = e / D, x = e - y * D;
      if (((unsigned)(x-1) < (unsigned)(D-2)) && ((unsigned)(y-1) < (unsigned)(D-2))) m = fmaxf(m, v.z); }
    { int e = e0 + 3, y = e / D, x = e - y * D;
      if (((unsigned)(x-1) < (unsigned)(D-2)) && ((unsigned)(y-1) < (unsigned)(D-2))) m = fmaxf(m, v.w); }
    return m;
  }
}

template <int L>
__device__ void bodyA(int local, const float* __restrict__ in, float* ws) {
  constexpr int D = DIMS_[L], HW = D * D, HW4 = HW / 4;
  constexpr int BPC = (HW4 + 4095) / 4096;
  int ch = local / BPC, chunk = local % BPC;
  int nvec = HW4 - chunk * 4096; if (nvec > 4096) nvec = 4096;
  const float4* pv = (const float4*)(in + (size_t)ch * HW) + (size_t)chunk * 4096;
  int t = threadIdx.x, last = nvec - 1, base = chunk * 4096;
  float mx = 0.0f;
  LDC(a0,0);  LDC(a1,1);  LDC(a2,2);  LDC(a3,3);
  LDC(a4,4);  LDC(a5,5);  LDC(a6,6);  LDC(a7,7);
  LDC(a8,8);  LDC(a9,9);  LDC(a10,10); LDC(a11,11);
  LDC(a12,12); LDC(a13,13); LDC(a14,14); LDC(a15,15);
#define ASTEP(nm, ii) do { int vi = (ii) * TPB + t;                                  \
    if (vi <= last) mx = fmaxf(mx, zbmax4<D>(nm, base + vi)); } while (0)
  ASTEP(a0,0);  ASTEP(a1,1);  ASTEP(a2,2);  ASTEP(a3,3);
  ASTEP(a4,4);  ASTEP(a5,5);  ASTEP(a6,6);  ASTEP(a7,7);
  ASTEP(a8,8);  ASTEP(a9,9);  ASTEP(a10,10); ASTEP(a11,11);
  ASTEP(a12,12); ASTEP(a13,13); ASTEP(a14,14); ASTEP(a15,15);
#undef ASTEP
  WREDM(mx);
  __shared__ float smx[4];
  int w = t >> 6;
  if ((t & 63) == 0) smx[w] = mx;
  __syncthreads();
  if (t == 0) {
    mx = fmaxf(fmaxf(smx[0], smx[1]), fmaxf(smx[2], smx[3]));
    atomicMax((unsigned*)ws + O_CHMAX + CHB_[L] + ch, __float_as_uint(mx));  // values >= 0
  }
}
__global__ void kA(P p) {
  int b = blockIdx.x;
  if      (b <  960) bodyA<0>(b,        p.in[0], p.ws);
  else if (b < 1472) bodyA<1>(b -  960, p.in[1], p.ws);
  else if (b < 1728) bodyA<2>(b - 1472, p.in[2], p.ws);
  else if (b < 2240) bodyA<3>(b - 1728, p.in[3], p.ws);
  else               bodyA<4>(b - 2240, p.in[4], p.ws);
}

// ---- pass B: RAW monotone compare counts (no border logic in hot loop) ----
// H/G slots 0..4 hold count(v_raw >= th[k]) over the whole channel. Border
// blocks subtract raw border contributions; kS adds the analytic zero-border
// term and converts monotone counts to bins. All state = named scalars
// (round-2 lesson: local arrays got promote-alloca'd into 48KB LDS/block,
// halving occupancy). 16 clamped loads straight-line.
template <int L>
__device__ void bodyB(int local, const float* __restrict__ in, float* ws) {
  constexpr int D = DIMS_[L], HW = D * D, HW4 = HW / 4;
  constexpr int BPC = (HW4 + 4095) / 4096;
  int ch = local / BPC, chunk = local % BPC;
  int g = CHB_[L] + ch;
  float rng = ws[O_CHMAX + g];   // mn == 0
  MK_THR_SCALAR(rng);
  int nvec = HW4 - chunk * 4096; if (nvec > 4096) nvec = 4096;
  const float4* pv = (const float4*)(in + (size_t)ch * HW) + (size_t)chunk * 4096;
  int t = threadIdx.x, last = nvec - 1;
  unsigned h0=0,h1=0,h2=0,h3=0,h4=0,g0=0,g1=0,g2=0,g3=0,g4=0;
  LDC(a0,0);  LDC(a1,1);  LDC(a2,2);  LDC(a3,3);
  LDC(a4,4);  LDC(a5,5);  LDC(a6,6);  LDC(a7,7);
  LDC(a8,8);  LDC(a9,9);  LDC(a10,10); LDC(a11,11);
  LDC(a12,12); LDC(a13,13); LDC(a14,14); LDC(a15,15);
#define BSTEP(nm, ii) do { if ((ii) * TPB + t <= last) {                             \
    CNT1(nm.x); CNT1(nm.y); CNT1(nm.z); CNT1(nm.w); } } while (0)
  BSTEP(a0,0);  BSTEP(a1,1);  BSTEP(a2,2);  BSTEP(a3,3);
  BSTEP(a4,4);  BSTEP(a5,5);  BSTEP(a6,6);  BSTEP(a7,7);
  BSTEP(a8,8);  BSTEP(a9,9);  BSTEP(a10,10); BSTEP(a11,11);
  BSTEP(a12,12); BSTEP(a13,13); BSTEP(a14,14); BSTEP(a15,15);
#undef BSTEP
  WREDS(h0); WREDS(h1); WREDS(h2); WREDS(h3); WREDS(h4);
  WREDS(g0); WREDS(g1); WREDS(g2); WREDS(g3); WREDS(g4);
  if ((t & 63) == 0) {
    unsigned* H = (unsigned*)ws + O_HIST + g * 6;
    unsigned* G = (unsigned*)ws + O_GCNT + g * 6;
    atomicAdd(H + 0, h0); atomicAdd(H + 1, h1); atomicAdd(H + 2, h2);
    atomicAdd(H + 3, h3); atomicAdd(H + 4, h4);
    atomicAdd(G + 0, g0); atomicAdd(G + 1, g1); atomicAdd(G + 2, g2);
    atomicAdd(G + 3, g3); atomicAdd(G + 4, g4);
  }
}

// border-fix blocks: one block per channel, subtract raw border compare counts
__device__ void bodyBborder(int ch, P p) {
  float* ws = p.ws;
  int l = (ch < 64) ? 0 : (ch < 192) ? 1 : (ch < 448) ? 2 : (ch < 960) ? 3 : 4;
  int D = DIMS_[l];
  const float* src = p.in[l] + (size_t)(ch - CHB_[l]) * (D * D);
  float rng = ws[O_CHMAX + ch];   // mn == 0
  MK_THR_SCALAR(rng);
  unsigned h0=0,h1=0,h2=0,h3=0,h4=0,g0=0,g1=0,g2=0,g3=0,g4=0;
  int nb = 4 * D - 4;
  for (int e = threadIdx.x; e < nb; e += TPB) {
    int x, y;
    if (e < D)          { y = 0; x = e; }
    else if (e < 2 * D) { y = D - 1; x = e - D; }
    else {
      int e2 = e - 2 * D;
      y = 1 + (e2 >> 1);
      x = (e2 & 1) ? (D - 1) : 0;
    }
    float v = src[y * D + x];
    CNT1(v);
  }
  WREDS(h0); WREDS(h1); WREDS(h2); WREDS(h3); WREDS(h4);
  WREDS(g0); WREDS(g1); WREDS(g2); WREDS(g3); WREDS(g4);
  if ((threadIdx.x & 63) == 0) {
    unsigned* H = (unsigned*)ws + O_HIST + ch * 6;
    unsigned* G = (unsigned*)ws + O_GCNT + ch * 6;
    atomicSub(H + 0, h0); atomicSub(H + 1, h1); atomicSub(H + 2, h2);
    atomicSub(H + 3, h3); atomicSub(H + 4, h4);
    atomicSub(G + 0, g0); atomicSub(G + 1, g1); atomicSub(G + 2, g2);
    atomicSub(G + 3, g3); atomicSub(G + 4, g4);
  }
}

__global__ void kB(P p) {
  int b = blockIdx.x;
  if (b >= 2752) { bodyBborder(b - 2752, p); return; }
  if      (b <  960) bodyB<0>(b,        p.in[0], p.ws);
  else if (b < 1472) bodyB<1>(b -  960, p.in[1], p.ws);
  else if (b < 1728) bodyB<2>(b - 1472, p.in[2], p.ws);
  else if (b < 2240) bodyB<3>(b - 1728, p.in[3], p.ws);
  else               bodyB<4>(b - 2240, p.in[4], p.ws);
}

// ---------------- kernel S: per-channel LUT construction ----------------
__global__ void kS(P p) {
  int ch = blockIdx.x * TPB + threadIdx.x;
  if (ch >= TOTCH) return;
  float* ws = p.ws;
  int l = (ch < 64) ? 0 : (ch < 192) ? 1 : (ch < 448) ? 2 : (ch < 960) ? 3 : 4;
  int D = DIMS_[l];
  int HW = D * D;
  int c0 = ch - CHB_[l];
  // ---- reconstruct border-zeroed bin counts from raw monotone counts ----
  unsigned* H = (unsigned*)ws + O_HIST + ch * 6;
  unsigned* G = (unsigned*)ws + O_GCNT + ch * 6;
  unsigned cH[5], cG[5];
  #pragma unroll
  for (int k = 0; k < 5; k++) { cH[k] = H[k]; cG[k] = G[k]; }
  float mxc = ws[O_CHMAX + ch];
  float thh[5], tg[5];
  mk_hthr(0.0f, mxc, thh);
  mk_gthr(0.0f, mxc, tg);
  unsigned bcnt = (unsigned)(4 * D - 4);
  unsigned czH[5], czG[5];
  #pragma unroll
  for (int k = 0; k < 5; k++) {
    czH[k] = cH[k] + bcnt * (unsigned)(0.0f >= thh[k]);
    czG[k] = cG[k] + bcnt * (unsigned)(0.0f >= tg[k]);
  }
  unsigned hc[6], gc[6];
  hc[0] = (unsigned)HW - czH[0]; hc[5] = czH[4];
  gc[0] = (unsigned)HW - czG[0]; gc[5] = czG[4];
  #pragma unroll
  for (int k = 1; k < 5; k++) { hc[k] = czH[k - 1] - czH[k]; gc[k] = czG[k - 1] - czG[k]; }
  // ---- original LUT math ----
  float HWf = (float)HW;
  float nh[6];
  #pragma unroll
  for (int k = 0; k < 6; k++) nh[k] = -logf((float)hc[k] / HWf + 1e-4f);
  float dmn = INFINITY, dmx = -INFINITY;
  #pragma unroll
  for (int k = 0; k < 6; k++) if (gc[k]) { dmn = fminf(dmn, nh[k]); dmx = fmaxf(dmx, nh[k]); }
  float dr = dmx - dmn;
  float dstn[6];
  #pragma unroll
  for (int k = 0; k < 6; k++) dstn[k] = (dr == 0.0f) ? 0.0f : ((nh[k] - dmn) / dr);
  float maxv = (dr == 0.0f) ? 0.0f : 1.0f;
  double s1 = 0.0;
  #pragma unroll
  for (int k = 0; k < 6; k++) s1 += (double)gc[k] * (double)dstn[k];
  float mean1 = (float)(s1 / (double)HW);
  float w1 = maxv - mean1; w1 *= w1;
  float lut1[6];
  #pragma unroll
  for (int k = 0; k < 6; k++) lut1[k] = dstn[k] * w1;
  int gb = (0.0f >= tg[0]) + (0.0f >= tg[1]) + (0.0f >= tg[2]) + (0.0f >= tg[3]) + (0.0f >= tg[4]);
  float lmn, lmx;
  double s2 = 0.0;
  if (c0 == 0) {   // channel 0 keeps its border
    lmn = INFINITY; lmx = -INFINITY;
    #pragma unroll
    for (int k = 0; k < 6; k++) if (gc[k]) {
      lmn = fminf(lmn, lut1[k]); lmx = fmaxf(lmx, lut1[k]);
      s2 += (double)gc[k] * (double)lut1[k];
    }
  } else {
    lmn = 0.0f; lmx = 0.0f;   // border zeros present
    #pragma unroll
    for (int k = 0; k < 6; k++) {
      unsigned ic = gc[k] - ((k == gb) ? bcnt : 0u);
      if (ic) {
        lmn = fminf(lmn, lut1[k]); lmx = fmaxf(lmx, lut1[k]);
        s2 += (double)ic * (double)lut1[k];
      }
    }
  }
  float mean2 = (float)(s2 / (double)HW);
  float w2 = lmx - mean2; w2 *= w2;
  float r2 = lmx - lmn;
  float lout[6];
  #pragma unroll
  for (int k = 0; k < 6; k++) lout[k] = (r2 == 0.0f) ? 0.0f : (((lut1[k] - lmn) / r2) * w2);
  // aligned LUT record: gthr at [0..4], lut at [8..13]
  float* T = ws + O_CLUT + (size_t)ch * 16;
  #pragma unroll
  for (int k = 0; k < 5; k++) T[k] = tg[k];
  #pragma unroll
  for (int k = 0; k < 6; k++) T[8 + k] = lout[k];
  float bc = (c0 == 0) ? lout[gb] : ((r2 == 0.0f) ? 0.0f : (((0.0f - lmn) / r2) * w2));
  atomicAdd(ws + O_BSUM + l, bc);
}

// ---- pass C: proc = sum_c LUT[gb_c(v)] ----
// (64-float4 tile) x (64-channel chunk); 4 waves split the 64 channels.
// All 16 channel loads issued straight-line (named scalars), LUT in LDS.
template <int L>
__device__ void bodyC(int local, const float* __restrict__ in, float* ws,
                      float* slut, float* sred) {
  constexpr int D = DIMS_[L], HW = D * D, HW4 = HW / 4, C = CHS_[L];
  constexpr int NT  = (HW4 + 63) / 64;   // tiles per layer
  constexpr int NCH = C / 64;            // channel chunks
  int tile = local % NT, chunk = local / NT;
  int cbase = CHB_[L] + chunk * 64;
  int t = threadIdx.x, lane = t & 63, w = t >> 6;
  const float* gl = ws + O_CLUT + (size_t)cbase * 16;
  for (int i = t; i < 1024; i += TPB) slut[i] = gl[i];
  __syncthreads();
  int p4 = tile * 64 + lane;
  bool valid = p4 < HW4;
  float r0 = 0.0f, r1 = 0.0f, r2 = 0.0f, r3 = 0.0f;
  if (valid) {
    const float4* bp = (const float4*)in + (size_t)(chunk * 64 + w * 16) * HW4 + p4;
    const float* su = slut + (w * 16) * 16;
    float4 va0 = bp[0],                 va1 = bp[(size_t)HW4],
           va2 = bp[(size_t)2 * HW4],   va3 = bp[(size_t)3 * HW4],
           va4 = bp[(size_t)4 * HW4],   va5 = bp[(size_t)5 * HW4],
           va6 = bp[(size_t)6 * HW4],   va7 = bp[(size_t)7 * HW4],
           va8 = bp[(size_t)8 * HW4],   va9 = bp[(size_t)9 * HW4],
           va10 = bp[(size_t)10 * HW4], va11 = bp[(size_t)11 * HW4],
           va12 = bp[(size_t)12 * HW4], va13 = bp[(size_t)13 * HW4],
           va14 = bp[(size_t)14 * HW4], va15 = bp[(size_t)15 * HW4];
#define CPROC(vv, c) do {                                                            \
    float q0 = su[(c)*16+0], q1 = su[(c)*16+1], q2 = su[(c)*16+2],                   \
          q3 = su[(c)*16+3], q4 = su[(c)*16+4];                                      \
    float l0 = su[(c)*16+8],  l1 = su[(c)*16+9],  l2 = su[(c)*16+10],                \
          l3 = su[(c)*16+11], l4 = su[(c)*16+12], l5 = su[(c)*16+13];                \
    float s;                                                                         \
    s = (vv.x >= q0) ? l1 : l0; s = (vv.x >= q1) ? l2 : s; s = (vv.x >= q2) ? l3 : s;\
    s = (vv.x >= q3) ? l4 : s;  s = (vv.x >= q4) ? l5 : s; r0 += s;                  \
    s = (vv.y >= q0) ? l1 : l0; s = (vv.y >= q1) ? l2 : s; s = (vv.y >= q2) ? l3 : s;\
    s = (vv.y >= q3) ? l4 : s;  s = (vv.y >= q4) ? l5 : s; r1 += s;                  \
    s = (vv.z >= q0) ? l1 : l0; s = (vv.z >= q1) ? l2 : s; s = (vv.z >= q2) ? l3 : s;\
    s = (vv.z >= q3) ? l4 : s;  s = (vv.z >= q4) ? l5 : s; r2 += s;                  \
    s = (vv.w >= q0) ? l1 : l0; s = (vv.w >= q1) ? l2 : s; s = (vv.w >= q2) ? l3 : s;\
    s = (vv.w >= q3) ? l4 : s;  s = (vv.w >= q4) ? l5 : s; r3 += s; } while (0)
    CPROC(va0,0);  CPROC(va1,1);  CPROC(va2,2);  CPROC(va3,3);
    CPROC(va4,4);  CPROC(va5,5);  CPROC(va6,6);  CPROC(va7,7);
    CPROC(va8,8);  CPROC(va9,9);  CPROC(va10,10); CPROC(va11,11);
    CPROC(va12,12); CPROC(va13,13); CPROC(va14,14); CPROC(va15,15);
#undef CPROC
  }
  sred[0 * 256 + w * 64 + lane] = r0;
  sred[1 * 256 + w * 64 + lane] = r1;
  sred[2 * 256 + w * 64 + lane] = r2;
  sred[3 * 256 + w * 64 + lane] = r3;
  __syncthreads();
  if (w == 0 && valid) {
    float o0 = sred[lane]       + sred[64 + lane]       + sred[128 + lane]       + sred[192 + lane];
    float o1 = sred[256 + lane] + sred[256 + 64 + lane] + sred[256 + 128 + lane] + sred[256 + 192 + lane];
    float o2 = sred[512 + lane] + sred[512 + 64 + lane] + sred[512 + 128 + lane] + sred[512 + 192 + lane];
    float o3 = sred[768 + lane] + sred[768 + 64 + lane] + sred[768 + 128 + lane] + sred[768 + 192 + lane];
    float bs = ws[O_BSUM + L];
    float* procL = ws + O_PROC + PROCB_[L];
    int px0 = p4 * 4;
#define BORDFIX(oj, jj) do { int px = px0 + (jj), y = px / D, x = px - y * D;        \
      bool inr = ((unsigned)(x - 1) < (unsigned)(D - 2)) &&                          \
                 ((unsigned)(y - 1) < (unsigned)(D - 2));                            \
      if (!inr) oj = bs; } while (0)
    if constexpr (NCH == 1) {
      BORDFIX(o0,0); BORDFIX(o1,1); BORDFIX(o2,2); BORDFIX(o3,3);
      ((float4*)procL)[p4] = make_float4(o0, o1, o2, o3);
    } else {
#define BORDADD(oj, jj) do { int px = px0 + (jj), y = px / D, x = px - y * D;        \
      bool inr = ((unsigned)(x - 1) < (unsigned)(D - 2)) &&                          \
                 ((unsigned)(y - 1) < (unsigned)(D - 2));                            \
      if (inr) atomicAdd(procL + px, oj);                                            \
      else if (chunk == 0) procL[px] = bs; } while (0)
      BORDADD(o0,0); BORDADD(o1,1); BORDADD(o2,2); BORDADD(o3,3);
#undef BORDADD
    }
#undef BORDFIX
  }
}
__global__ __launch_bounds__(TPB) void kC(P p) {
  __shared__ float slut[1024];
  __shared__ float sred[1024];
  int b = blockIdx.x;
  if      (b <  900) bodyC<0>(b,        p.in[0], p.ws, slut, sred);
  else if (b < 1350) bodyC<1>(b -  900, p.in[1], p.ws, slut, sred);
  else if (b < 1578) bodyC<2>(b - 1350, p.in[2], p.ws, slut, sred);
  else if (b < 1698) bodyC<3>(b - 1578, p.in[3], p.ws, slut, sred);
  else               bodyC<4>(b - 1698, p.in[4], p.ws, slut, sred);
}

// ---------------- pass D: per-layer proc min/max ----------------
template <int L>
__device__ void bodyD(int chunk, float* ws) {
  constexpr int HW = DIMS_[L] * DIMS_[L];
  const float* pr = ws + O_PROC + PROCB_[L];
  int t = threadIdx.x;
  float mn = INFINITY, mx = 0.0f;   // proc >= 0
  #pragma unroll
  for (int i = 0; i < 16; i++) {
    int idx = chunk * 4096 + i * TPB + t;
    if (idx < HW) { float v = pr[idx]; mn = fminf(mn, v); mx = fmaxf(mx, v); }
  }
  for (int o = 32; o; o >>= 1) { mn = fminf(mn, __shfl_down(mn, o)); mx = fmaxf(mx, __shfl_down(mx, o)); }
  __shared__ float smn[4], smx[4];
  int w = t >> 6;
  if ((t & 63) == 0) { smn[w] = mn; smx[w] = mx; }
  __syncthreads();
  if (t == 0) {
    mn = fminf(fminf(smn[0], smn[1]), fminf(smn[2], smn[3]));
    mx = fmaxf(fmaxf(smx[0], smx[1]), fmaxf(smx[2], smx[3]));
    atomicMin((unsigned*)ws + O_PMIN + L, __float_as_uint(mn));
    atomicMax((unsigned*)ws + O_PMAX + L, __float_as_uint(mx));
  }
}
__global__ void kD(P p) {
  int b = blockIdx.x;
  if      (b < 57) bodyD<0>(b,      p.ws);
  else if (b < 72) bodyD<1>(b - 57, p.ws);
  else if (b < 76) bodyD<2>(b - 72, p.ws);
  else if (b < 77) bodyD<3>(b - 76, p.ws);
  else             bodyD<4>(b - 77, p.ws);
}

// ---- pass F: normalize(proc,0,1) + threshold + jax bilinear resize, fused layer stats ----
template <int L>
__device__ float bodyF(int px, float* ws) {
  constexpr int D = DIMS_[L];
  constexpr float INV = (float)D / 240.0f;
  constexpr float KS = (INV > 1.0f) ? INV : 1.0f;
  int oy = px / 240, ox = px - oy * 240;
  float mnv = __uint_as_float(((unsigned*)ws)[O_PMIN + L]);
  float mxv = __uint_as_float(((unsigned*)ws)[O_PMAX + L]);
  float pr = mxv - mnv;
  const float* procL = ws + O_PROC + PROCB_[L];
  float sfy = ((float)oy + 0.5f) * INV - 0.5f;
  float sfx = ((float)ox + 0.5f) * INV - 0.5f;
  int y0 = (int)ceilf(sfy - KS);  if (y0 < 0) y0 = 0;
  int y1 = (int)floorf(sfy + KS); if (y1 > D - 1) y1 = D - 1;
  int x0 = (int)ceilf(sfx - KS);  if (x0 < 0) x0 = 0;
  int x1 = (int)floorf(sfx + KS); if (x1 > D - 1) x1 = D - 1;
  float wsx = 0.0f;
  for (int jx = x0; jx <= x1; jx++) wsx += fmaxf(1.0f - fabsf(sfx - (float)jx) / KS, 0.0f);
  float acc = 0.0f, wsy = 0.0f;
  for (int jy = y0; jy <= y1; jy++) {
    float wy = fmaxf(1.0f - fabsf(sfy - (float)jy) / KS, 0.0f);
    wsy += wy;
    if (wy > 0.0f) {
      const float* row = procL + jy * D;
      float rs = 0.0f;
      for (int jx = x0; jx <= x1; jx++) {
        float wx = fmaxf(1.0f - fabsf(sfx - (float)jx) / KS, 0.0f);
        if (wx > 0.0f) {
          float v = row[jx];
          float tv = (pr == 0.0f) ? 0.0f : ((v - mnv) / pr);
          tv = (tv < 0.2f) ? 0.0f : tv;
          rs += wx * tv;
        }
      }
      acc += wy * rs;
    }
  }
  return acc / (wsy * wsx);
}
__global__ void kF(P p) {
  float* ws = p.ws;
  int b = blockIdx.x, l = b / 225;
  int px = (b - l * 225) * TPB + threadIdx.x;
  float res;
  switch (l) {
    case 0: res = bodyF<0>(px, ws); break;
    case 1: res = bodyF<1>(px, ws); break;
    case 2: res = bodyF<2>(px, ws); break;
    case 3: res = bodyF<3>(px, ws); break;
    default: res = bodyF<4>(px, ws); break;
  }
  ws[O_RESZ + l * 57600 + px] = res;
  float mn = res, mx = res, s = res;
  for (int o = 32; o; o >>= 1) {
    mn = fminf(mn, __shfl_down(mn, o));
    mx = fmaxf(mx, __shfl_down(mx, o));
    s += __shfl_down(s, o);
  }
  __shared__ float smn[4], smx[4], ssm[4];
  int t = threadIdx.x, w = t >> 6;
  if ((t & 63) == 0) { smn[w] = mn; smx[w] = mx; ssm[w] = s; }
  __syncthreads();
  if (t == 0) {
    mn = fminf(fminf(smn[0], smn[1]), fminf(smn[2], smn[3]));
    mx = fmaxf(fmaxf(smx[0], smx[1]), fmaxf(smx[2], smx[3]));
    s = ssm[0] + ssm[1] + ssm[2] + ssm[3];
    atomicMin((unsigned*)ws + O_S3MIN + l, __float_as_uint(mn));
    atomicMax((unsigned*)ws + O_S3MAX + l, __float_as_uint(mx));
    atomicAdd(ws + O_S3SUM + l, s);
  }
}

// ---------------- G2: final ponder + normalize(.,0,256), groups + sum ----------------
__global__ void kG2(P p, float* __restrict__ out) {
  float* ws = p.ws;
  int px = blockIdx.x * TPB + threadIdx.x;   // 225*256 == 57600
  float sum = 0.0f;
  #pragma unroll
  for (int l = 0; l < 5; l++) {
    float v = ws[O_RESZ + l * 57600 + px];
    float mn3 = __uint_as_float(((unsigned*)ws)[O_S3MIN + l]);
    float mx3 = __uint_as_float(((unsigned*)ws)[O_S3MAX + l]);
    float mean3 = ws[O_S3SUM + l] / 57600.0f;
    float r3 = mx3 - mn3;
    float ov;
    if (r3 == 0.0f) ov = 0.0f;
    else {
      float w3 = mx3 - mean3; w3 *= w3;
      if (w3 == 0.0f) ov = 0.0f;
      else ov = ((v - mn3) / r3) * w3 / w3 * 256.0f;
    }
    out[57600 + px * 5 + l] = ov;
    sum += ov;
  }
  out[px] = sum;
}

extern "C" void kernel_launch(void* const* d_in, const int* in_sizes, int n_in,
                              void* d_out, int out_size, void* d_ws, size_t ws_size,
                              hipStream_t stream) {
  (void)in_sizes; (void)n_in; (void)out_size; (void)ws_size;
  P p;
  for (int i = 0; i < 5; i++) p.in[i] = (const float*)d_in[i];
  p.ws = (float*)d_ws;
  float* out = (float*)d_out;

  k_init<<<(N_INIT + TPB - 1) / TPB, TPB, 0, stream>>>(p.ws);
  kA  <<<2752, TPB, 0, stream>>>(p);
  kB  <<<2752 + TOTCH, TPB, 0, stream>>>(p);   // +1472 border-fix blocks
  kS  <<<6,    TPB, 0, stream>>>(p);
  kC  <<<1730, TPB, 0, stream>>>(p);
  kD  <<<78,   TPB, 0, stream>>>(p);
  kF  <<<1125, TPB, 0, stream>>>(p);
  kG2 <<<225,  TPB, 0, stream>>>(p, out);
}

// Round 4
// 295.274 us; speedup vs baseline: 1.2178x; 1.2178x over previous
//
#include <hip/hip_runtime.h>
#include <math.h>

#define TPB 256

// ---------------- layer geometry ----------------
constexpr int DIMS_[5]  = {480, 240, 120, 60, 30};
constexpr int CHS_ [5]  = {64, 128, 256, 512, 512};
constexpr int CHB_ [5]  = {0, 64, 192, 448, 960};
constexpr int TOTCH     = 1472;
constexpr int PROCB_[5] = {0, 230400, 288000, 302400, 306000};
constexpr int PROCTOT   = 306900;

// ---------------- ws layout (4-byte words) ----------------
constexpr int O_CHMIN = 0;                  // f32 [1472]  (UNUSED: min==0 by construction)
constexpr int O_CHMAX = 1472;               // f32 [1472]
constexpr int O_HIST  = 2944;               // u32 [1472*6]: slots 0..4 = raw count(v>=th[k])
constexpr int O_GCNT  = 11776;              // u32 [1472*6]: slots 0..4 = raw count(v>=tg[k])
constexpr int O_CLUT  = 20608;              // f32 [1472*16]: gthr[0..4], pad, lut[8..13]
constexpr int O_BSUM  = O_CLUT + 16 * 1472; // 44160: f32 [5]
constexpr int O_PMIN  = O_BSUM + 5;         // u32 [5]
constexpr int O_PMAX  = O_PMIN + 5;         // u32 [5]
constexpr int O_S3MIN = O_PMAX + 5;         // u32 [5]
constexpr int O_S3MAX = O_S3MIN + 5;        // u32 [5]
constexpr int O_S3SUM = O_S3MAX + 5;        // f32 [5]
constexpr int O_PROC  = 44192;              // f32 [306900] (zero-init; chunked layers atomicAdd)
constexpr int O_RESZ  = O_PROC + PROCTOT;   // f32 [5*57600]
constexpr int N_INIT  = O_PROC + PROCTOT;   // init range

struct P {
  const float* in[5];
  float* ws;
};

// ---------------- threshold helpers (array form: kS only) ----------------
__device__ __forceinline__ void mk_hthr(float mn, float rng, float* th) {
  if (rng == 0.0f) { th[0]=th[1]=th[2]=th[3]=th[4]=INFINITY; return; }
  th[0] = mn + rng * (1.0f / 6.0f); th[1] = mn + rng * (2.0f / 6.0f);
  th[2] = mn + rng * (3.0f / 6.0f); th[3] = mn + rng * (4.0f / 6.0f);
  th[4] = mn + rng * (5.0f / 6.0f);
}
__device__ __forceinline__ void mk_gthr(float mn, float rng, float* tg) {
  if (rng == 0.0f) { tg[0]=tg[1]=tg[2]=tg[3]=tg[4]=INFINITY; return; }
  tg[0] = mn + rng * (2.0f / 1536.0f); tg[1] = mn + rng * (3.0f / 1536.0f);
  tg[2] = mn + rng * (4.0f / 1536.0f); tg[3] = mn + rng * (5.0f / 1536.0f);
  tg[4] = mn + rng * (6.0f / 1536.0f);
}

// scalar threshold block (mn == 0): defines th0..th4, tg0..tg4 from rng
#define MK_THR_SCALAR(rng)                                                          \
  float th0, th1, th2, th3, th4, tg0, tg1, tg2, tg3, tg4;                           \
  if ((rng) == 0.0f) {                                                              \
    th0=th1=th2=th3=th4=tg0=tg1=tg2=tg3=tg4=INFINITY;                               \
  } else {                                                                          \
    th0 = (rng) * (1.0f/6.0f);    th1 = (rng) * (2.0f/6.0f);                        \
    th2 = (rng) * (3.0f/6.0f);    th3 = (rng) * (4.0f/6.0f);                        \
    th4 = (rng) * (5.0f/6.0f);                                                      \
    tg0 = (rng) * (2.0f/1536.0f); tg1 = (rng) * (3.0f/1536.0f);                     \
    tg2 = (rng) * (4.0f/1536.0f); tg3 = (rng) * (5.0f/1536.0f);                     \
    tg4 = (rng) * (6.0f/1536.0f);                                                   \
  }

// per-element raw compare-count update (pure VALU: v_cmp + v_addc)
#define CNT1(x) do {                                                                \
  h0 += ((x) >= th0); h1 += ((x) >= th1); h2 += ((x) >= th2);                       \
  h3 += ((x) >= th3); h4 += ((x) >= th4);                                           \
  g0 += ((x) >= tg0); g1 += ((x) >= tg1); g2 += ((x) >= tg2);                       \
  g3 += ((x) >= tg3); g4 += ((x) >= tg4); } while (0)
#define CNT4(v) do { CNT1(v.x); CNT1(v.y); CNT1(v.z); CNT1(v.w); } while (0)

// wave-64 sum / max reductions on a named scalar
#define WREDS(v) do { v += __shfl_down(v,32); v += __shfl_down(v,16);               \
  v += __shfl_down(v,8); v += __shfl_down(v,4); v += __shfl_down(v,2);              \
  v += __shfl_down(v,1); } while (0)
#define WREDM(v) do { v = fmaxf(v, __shfl_down(v,32)); v = fmaxf(v, __shfl_down(v,16)); \
  v = fmaxf(v, __shfl_down(v,8)); v = fmaxf(v, __shfl_down(v,4));                   \
  v = fmaxf(v, __shfl_down(v,2)); v = fmaxf(v, __shfl_down(v,1)); } while (0)

// ---------------- init ----------------
__global__ void k_init(float* ws) {
  int i = blockIdx.x * TPB + threadIdx.x;
  if (i >= N_INIT) return;
  unsigned v = 0u;
  if (i >= O_PMIN  && i < O_PMAX)  v = 0x7F800000u;       // pmin = +inf
  else if (i >= O_S3MIN && i < O_S3MAX) v = 0x7F800000u;  // s3min
  ((unsigned*)ws)[i] = v;
}

// ---------------- pass A: per-channel MAX of border-zeroed map ----------------
// min == 0 always (borders zeroed, inputs nonneg) -> max-only.
// Depth-8 load groups inside a 128-VGPR budget (__launch_bounds__(256,4)):
// 8 float4 = 32 dwords live + scalars ~ 60 VGPR peak -> registers, no spill
// (round-2/3 lesson: 16 forced-live float4s blew the default 64-VGPR budget
// and spilled 192 B/thread to LDS, capping occupancy at 3 blocks/CU).
template <int D>
__device__ __forceinline__ float zbmax4(float4 v, int f4i) {
  if constexpr (D % 4 == 0) {
    constexpr int DQ = D / 4;
    int y = f4i / DQ, xq = f4i - y * DQ;
    if (y == 0 || y == D - 1) return 0.0f;
    if (xq == 0)      v.x = 0.0f;
    if (xq == DQ - 1) v.w = 0.0f;
    return fmaxf(fmaxf(v.x, v.y), fmaxf(v.z, v.w));
  } else {
    int e0 = f4i * 4;
    float m = 0.0f;
    { int e = e0,     y = e / D, x = e - y * D;
      if (((unsigned)(x-1) < (unsigned)(D-2)) && ((unsigned)(y-1) < (unsigned)(D-2))) m = fmaxf(m, v.x); }
    { int e = e0 + 1, y = e / D, x = e - y * D;
      if (((unsigned)(x-1) < (unsigned)(D-2)) && ((unsigned)(y-1) < (unsigned)(D-2))) m = fmaxf(m, v.y); }
    { int e = e0 + 2, y = e / D, x = e - y * D;
      if (((unsigned)(x-1) < (unsigned)(D-2)) && ((unsigned)(y-1) < (unsigned)(D-2))) m = fmaxf(m, v.z); }
    { int e = e0 + 3, y = e / D, x = e - y * D;
      if (((unsigned)(x-1) < (unsigned)(D-2)) && ((unsigned)(y-1) < (unsigned)(D-2))) m = fmaxf(m, v.w); }
    return m;
  }
}

template <int L>
__device__ void bodyA(int local, const float* __restrict__ in, float* ws) {
  constexpr int D = DIMS_[L], HW = D * D, HW4 = HW / 4;
  constexpr int BPC = (HW4 + 4095) / 4096;
  int ch = local / BPC, chunk = local % BPC;
  int nvec = HW4 - chunk * 4096; if (nvec > 4096) nvec = 4096;
  const float4* pv = (const float4*)(in + (size_t)ch * HW) + (size_t)chunk * 4096;
  int t = threadIdx.x, base = chunk * 4096;
  float mx = 0.0f;
  if (nvec == 4096) {
    const float4* q = pv + t;
    // group 1: 8 loads issued together, then compute
    float4 a0 = q[0],       a1 = q[TPB],     a2 = q[2 * TPB], a3 = q[3 * TPB],
           a4 = q[4 * TPB], a5 = q[5 * TPB], a6 = q[6 * TPB], a7 = q[7 * TPB];
    int i0 = base + t;
    mx = fmaxf(mx, zbmax4<D>(a0, i0));
    mx = fmaxf(mx, zbmax4<D>(a1, i0 + TPB));
    mx = fmaxf(mx, zbmax4<D>(a2, i0 + 2 * TPB));
    mx = fmaxf(mx, zbmax4<D>(a3, i0 + 3 * TPB));
    mx = fmaxf(mx, zbmax4<D>(a4, i0 + 4 * TPB));
    mx = fmaxf(mx, zbmax4<D>(a5, i0 + 5 * TPB));
    mx = fmaxf(mx, zbmax4<D>(a6, i0 + 6 * TPB));
    mx = fmaxf(mx, zbmax4<D>(a7, i0 + 7 * TPB));
    // group 2
    a0 = q[8 * TPB];  a1 = q[9 * TPB];  a2 = q[10 * TPB]; a3 = q[11 * TPB];
    a4 = q[12 * TPB]; a5 = q[13 * TPB]; a6 = q[14 * TPB]; a7 = q[15 * TPB];
    i0 = base + t + 8 * TPB;
    mx = fmaxf(mx, zbmax4<D>(a0, i0));
    mx = fmaxf(mx, zbmax4<D>(a1, i0 + TPB));
    mx = fmaxf(mx, zbmax4<D>(a2, i0 + 2 * TPB));
    mx = fmaxf(mx, zbmax4<D>(a3, i0 + 3 * TPB));
    mx = fmaxf(mx, zbmax4<D>(a4, i0 + 4 * TPB));
    mx = fmaxf(mx, zbmax4<D>(a5, i0 + 5 * TPB));
    mx = fmaxf(mx, zbmax4<D>(a6, i0 + 6 * TPB));
    mx = fmaxf(mx, zbmax4<D>(a7, i0 + 7 * TPB));
  } else {
    #pragma unroll 4
    for (int i = 0; i < 16; i++) {
      int vi = i * TPB + t;
      if (vi < nvec) mx = fmaxf(mx, zbmax4<D>(pv[vi], base + vi));
    }
  }
  WREDM(mx);
  __shared__ float smx[4];
  int w = t >> 6;
  if ((t & 63) == 0) smx[w] = mx;
  __syncthreads();
  if (t == 0) {
    mx = fmaxf(fmaxf(smx[0], smx[1]), fmaxf(smx[2], smx[3]));
    atomicMax((unsigned*)ws + O_CHMAX + CHB_[L] + ch, __float_as_uint(mx));  // values >= 0
  }
}
__global__ __launch_bounds__(TPB, 4) void kA(P p) {
  int b = blockIdx.x;
  if      (b <  960) bodyA<0>(b,        p.in[0], p.ws);
  else if (b < 1472) bodyA<1>(b -  960, p.in[1], p.ws);
  else if (b < 1728) bodyA<2>(b - 1472, p.in[2], p.ws);
  else if (b < 2240) bodyA<3>(b - 1728, p.in[3], p.ws);
  else               bodyA<4>(b - 2240, p.in[4], p.ws);
}

// ---- pass B: RAW monotone compare counts (no border logic in hot loop) ----
// H/G slots 0..4 hold count(v_raw >= th[k]) over the whole channel. Border
// blocks subtract raw border contributions; kS adds the analytic zero-border
// term and converts monotone counts to bins. Depth-8 groups, 128-VGPR budget.
template <int L>
__device__ void bodyB(int local, const float* __restrict__ in, float* ws) {
  constexpr int D = DIMS_[L], HW = D * D, HW4 = HW / 4;
  constexpr int BPC = (HW4 + 4095) / 4096;
  int ch = local / BPC, chunk = local % BPC;
  int g = CHB_[L] + ch;
  float rng = ws[O_CHMAX + g];   // mn == 0
  MK_THR_SCALAR(rng);
  int nvec = HW4 - chunk * 4096; if (nvec > 4096) nvec = 4096;
  const float4* pv = (const float4*)(in + (size_t)ch * HW) + (size_t)chunk * 4096;
  int t = threadIdx.x;
  unsigned h0=0,h1=0,h2=0,h3=0,h4=0,g0=0,g1=0,g2=0,g3=0,g4=0;
  if (nvec == 4096) {
    const float4* q = pv + t;
    float4 a0 = q[0],       a1 = q[TPB],     a2 = q[2 * TPB], a3 = q[3 * TPB],
           a4 = q[4 * TPB], a5 = q[5 * TPB], a6 = q[6 * TPB], a7 = q[7 * TPB];
    CNT4(a0); CNT4(a1); CNT4(a2); CNT4(a3);
    CNT4(a4); CNT4(a5); CNT4(a6); CNT4(a7);
    a0 = q[8 * TPB];  a1 = q[9 * TPB];  a2 = q[10 * TPB]; a3 = q[11 * TPB];
    a4 = q[12 * TPB]; a5 = q[13 * TPB]; a6 = q[14 * TPB]; a7 = q[15 * TPB];
    CNT4(a0); CNT4(a1); CNT4(a2); CNT4(a3);
    CNT4(a4); CNT4(a5); CNT4(a6); CNT4(a7);
  } else {
    #pragma unroll 4
    for (int i = 0; i < 16; i++) {
      int vi = i * TPB + t;
      if (vi < nvec) { float4 v = pv[vi]; CNT4(v); }
    }
  }
  WREDS(h0); WREDS(h1); WREDS(h2); WREDS(h3); WREDS(h4);
  WREDS(g0); WREDS(g1); WREDS(g2); WREDS(g3); WREDS(g4);
  if ((t & 63) == 0) {
    unsigned* H = (unsigned*)ws + O_HIST + g * 6;
    unsigned* G = (unsigned*)ws + O_GCNT + g * 6;
    atomicAdd(H + 0, h0); atomicAdd(H + 1, h1); atomicAdd(H + 2, h2);
    atomicAdd(H + 3, h3); atomicAdd(H + 4, h4);
    atomicAdd(G + 0, g0); atomicAdd(G + 1, g1); atomicAdd(G + 2, g2);
    atomicAdd(G + 3, g3); atomicAdd(G + 4, g4);
  }
}

// border-fix blocks: one block per channel, subtract raw border compare counts
__device__ void bodyBborder(int ch, P p) {
  float* ws = p.ws;
  int l = (ch < 64) ? 0 : (ch < 192) ? 1 : (ch < 448) ? 2 : (ch < 960) ? 3 : 4;
  int D = DIMS_[l];
  const float* src = p.in[l] + (size_t)(ch - CHB_[l]) * (D * D);
  float rng = ws[O_CHMAX + ch];   // mn == 0
  MK_THR_SCALAR(rng);
  unsigned h0=0,h1=0,h2=0,h3=0,h4=0,g0=0,g1=0,g2=0,g3=0,g4=0;
  int nb = 4 * D - 4;
  for (int e = threadIdx.x; e < nb; e += TPB) {
    int x, y;
    if (e < D)          { y = 0; x = e; }
    else if (e < 2 * D) { y = D - 1; x = e - D; }
    else {
      int e2 = e - 2 * D;
      y = 1 + (e2 >> 1);
      x = (e2 & 1) ? (D - 1) : 0;
    }
    float v = src[y * D + x];
    CNT1(v);
  }
  WREDS(h0); WREDS(h1); WREDS(h2); WREDS(h3); WREDS(h4);
  WREDS(g0); WREDS(g1); WREDS(g2); WREDS(g3); WREDS(g4);
  if ((threadIdx.x & 63) == 0) {
    unsigned* H = (unsigned*)ws + O_HIST + ch * 6;
    unsigned* G = (unsigned*)ws + O_GCNT + ch * 6;
    atomicSub(H + 0, h0); atomicSub(H + 1, h1); atomicSub(H + 2, h2);
    atomicSub(H + 3, h3); atomicSub(H + 4, h4);
    atomicSub(G + 0, g0); atomicSub(G + 1, g1); atomicSub(G + 2, g2);
    atomicSub(G + 3, g3); atomicSub(G + 4, g4);
  }
}

__global__ __launch_bounds__(TPB, 4) void kB(P p) {
  int b = blockIdx.x;
  if (b >= 2752) { bodyBborder(b - 2752, p); return; }
  if      (b <  960) bodyB<0>(b,        p.in[0], p.ws);
  else if (b < 1472) bodyB<1>(b -  960, p.in[1], p.ws);
  else if (b < 1728) bodyB<2>(b - 1472, p.in[2], p.ws);
  else if (b < 2240) bodyB<3>(b - 1728, p.in[3], p.ws);
  else               bodyB<4>(b - 2240, p.in[4], p.ws);
}

// ---------------- kernel S: per-channel LUT construction ----------------
__global__ void kS(P p) {
  int ch = blockIdx.x * TPB + threadIdx.x;
  if (ch >= TOTCH) return;
  float* ws = p.ws;
  int l = (ch < 64) ? 0 : (ch < 192) ? 1 : (ch < 448) ? 2 : (ch < 960) ? 3 : 4;
  int D = DIMS_[l];
  int HW = D * D;
  int c0 = ch - CHB_[l];
  // ---- reconstruct border-zeroed bin counts from raw monotone counts ----
  unsigned* H = (unsigned*)ws + O_HIST + ch * 6;
  unsigned* G = (unsigned*)ws + O_GCNT + ch * 6;
  unsigned cH[5], cG[5];
  #pragma unroll
  for (int k = 0; k < 5; k++) { cH[k] = H[k]; cG[k] = G[k]; }
  float mxc = ws[O_CHMAX + ch];
  float thh[5], tg[5];
  mk_hthr(0.0f, mxc, thh);
  mk_gthr(0.0f, mxc, tg);
  unsigned bcnt = (unsigned)(4 * D - 4);
  unsigned czH[5], czG[5];
  #pragma unroll
  for (int k = 0; k < 5; k++) {
    czH[k] = cH[k] + bcnt * (unsigned)(0.0f >= thh[k]);
    czG[k] = cG[k] + bcnt * (unsigned)(0.0f >= tg[k]);
  }
  unsigned hc[6], gc[6];
  hc[0] = (unsigned)HW - czH[0]; hc[5] = czH[4];
  gc[0] = (unsigned)HW - czG[0]; gc[5] = czG[4];
  #pragma unroll
  for (int k = 1; k < 5; k++) { hc[k] = czH[k - 1] - czH[k]; gc[k] = czG[k - 1] - czG[k]; }
  // ---- original LUT math ----
  float HWf = (float)HW;
  float nh[6];
  #pragma unroll
  for (int k = 0; k < 6; k++) nh[k] = -logf((float)hc[k] / HWf + 1e-4f);
  float dmn = INFINITY, dmx = -INFINITY;
  #pragma unroll
  for (int k = 0; k < 6; k++) if (gc[k]) { dmn = fminf(dmn, nh[k]); dmx = fmaxf(dmx, nh[k]); }
  float dr = dmx - dmn;
  float dstn[6];
  #pragma unroll
  for (int k = 0; k < 6; k++) dstn[k] = (dr == 0.0f) ? 0.0f : ((nh[k] - dmn) / dr);
  float maxv = (dr == 0.0f) ? 0.0f : 1.0f;
  double s1 = 0.0;
  #pragma unroll
  for (int k = 0; k < 6; k++) s1 += (double)gc[k] * (double)dstn[k];
  float mean1 = (float)(s1 / (double)HW);
  float w1 = maxv - mean1; w1 *= w1;
  float lut1[6];
  #pragma unroll
  for (int k = 0; k < 6; k++) lut1[k] = dstn[k] * w1;
  int gb = (0.0f >= tg[0]) + (0.0f >= tg[1]) + (0.0f >= tg[2]) + (0.0f >= tg[3]) + (0.0f >= tg[4]);
  float lmn, lmx;
  double s2 = 0.0;
  if (c0 == 0) {   // channel 0 keeps its border
    lmn = INFINITY; lmx = -INFINITY;
    #pragma unroll
    for (int k = 0; k < 6; k++) if (gc[k]) {
      lmn = fminf(lmn, lut1[k]); lmx = fmaxf(lmx, lut1[k]);
      s2 += (double)gc[k] * (double)lut1[k];
    }
  } else {
    lmn = 0.0f; lmx = 0.0f;   // border zeros present
    #pragma unroll
    for (int k = 0; k < 6; k++) {
      unsigned ic = gc[k] - ((k == gb) ? bcnt : 0u);
      if (ic) {
        lmn = fminf(lmn, lut1[k]); lmx = fmaxf(lmx, lut1[k]);
        s2 += (double)ic * (double)lut1[k];
      }
    }
  }
  float mean2 = (float)(s2 / (double)HW);
  float w2 = lmx - mean2; w2 *= w2;
  float r2 = lmx - lmn;
  float lout[6];
  #pragma unroll
  for (int k = 0; k < 6; k++) lout[k] = (r2 == 0.0f) ? 0.0f : (((lut1[k] - lmn) / r2) * w2);
  // aligned LUT record: gthr at [0..4], lut at [8..13]
  float* T = ws + O_CLUT + (size_t)ch * 16;
  #pragma unroll
  for (int k = 0; k < 5; k++) T[k] = tg[k];
  #pragma unroll
  for (int k = 0; k < 6; k++) T[8 + k] = lout[k];
  float bc = (c0 == 0) ? lout[gb] : ((r2 == 0.0f) ? 0.0f : (((0.0f - lmn) / r2) * w2));
  atomicAdd(ws + O_BSUM + l, bc);
}

// ---- pass C: proc = sum_c LUT[gb_c(v)] ----
// (64-float4 tile) x (64-channel chunk); 4 waves split the 64 channels.
// Depth-8 channel groups (named scalars) within the 128-VGPR budget.
template <int L>
__device__ void bodyC(int local, const float* __restrict__ in, float* ws,
                      float* slut, float* sred) {
  constexpr int D = DIMS_[L], HW = D * D, HW4 = HW / 4, C = CHS_[L];
  constexpr int NT  = (HW4 + 63) / 64;   // tiles per layer
  constexpr int NCH = C / 64;            // channel chunks
  int tile = local % NT, chunk = local / NT;
  int cbase = CHB_[L] + chunk * 64;
  int t = threadIdx.x, lane = t & 63, w = t >> 6;
  const float* gl = ws + O_CLUT + (size_t)cbase * 16;
  for (int i = t; i < 1024; i += TPB) slut[i] = gl[i];
  __syncthreads();
  int p4 = tile * 64 + lane;
  bool valid = p4 < HW4;
  float r0 = 0.0f, r1 = 0.0f, r2 = 0.0f, r3 = 0.0f;
  if (valid) {
    const float4* bp = (const float4*)in + (size_t)(chunk * 64 + w * 16) * HW4 + p4;
    const float* su = slut + (w * 16) * 16;
#define CPROC(vv, c) do {                                                            \
    float q0 = su[(c)*16+0], q1 = su[(c)*16+1], q2 = su[(c)*16+2],                   \
          q3 = su[(c)*16+3], q4 = su[(c)*16+4];                                      \
    float l0 = su[(c)*16+8],  l1 = su[(c)*16+9],  l2 = su[(c)*16+10],                \
          l3 = su[(c)*16+11], l4 = su[(c)*16+12], l5 = su[(c)*16+13];                \
    float s;                                                                         \
    s = (vv.x >= q0) ? l1 : l0; s = (vv.x >= q1) ? l2 : s; s = (vv.x >= q2) ? l3 : s;\
    s = (vv.x >= q3) ? l4 : s;  s = (vv.x >= q4) ? l5 : s; r0 += s;                  \
    s = (vv.y >= q0) ? l1 : l0; s = (vv.y >= q1) ? l2 : s; s = (vv.y >= q2) ? l3 : s;\
    s = (vv.y >= q3) ? l4 : s;  s = (vv.y >= q4) ? l5 : s; r1 += s;                  \
    s = (vv.z >= q0) ? l1 : l0; s = (vv.z >= q1) ? l2 : s; s = (vv.z >= q2) ? l3 : s;\
    s = (vv.z >= q3) ? l4 : s;  s = (vv.z >= q4) ? l5 : s; r2 += s;                  \
    s = (vv.w >= q0) ? l1 : l0; s = (vv.w >= q1) ? l2 : s; s = (vv.w >= q2) ? l3 : s;\
    s = (vv.w >= q3) ? l4 : s;  s = (vv.w >= q4) ? l5 : s; r3 += s; } while (0)
    // group 1: channels 0..7
    float4 va0 = bp[0],               va1 = bp[(size_t)HW4],
           va2 = bp[(size_t)2 * HW4], va3 = bp[(size_t)3 * HW4],
           va4 = bp[(size_t)4 * HW4], va5 = bp[(size_t)5 * HW4],
           va6 = bp[(size_t)6 * HW4], va7 = bp[(size_t)7 * HW4];
    CPROC(va0,0); CPROC(va1,1); CPROC(va2,2); CPROC(va3,3);
    CPROC(va4,4); CPROC(va5,5); CPROC(va6,6); CPROC(va7,7);
    // group 2: channels 8..15
    va0 = bp[(size_t)8 * HW4];  va1 = bp[(size_t)9 * HW4];
    va2 = bp[(size_t)10 * HW4]; va3 = bp[(size_t)11 * HW4];
    va4 = bp[(size_t)12 * HW4]; va5 = bp[(size_t)13 * HW4];
    va6 = bp[(size_t)14 * HW4]; va7 = bp[(size_t)15 * HW4];
    CPROC(va0,8);  CPROC(va1,9);  CPROC(va2,10); CPROC(va3,11);
    CPROC(va4,12); CPROC(va5,13); CPROC(va6,14); CPROC(va7,15);
#undef CPROC
  }
  sred[0 * 256 + w * 64 + lane] = r0;
  sred[1 * 256 + w * 64 + lane] = r1;
  sred[2 * 256 + w * 64 + lane] = r2;
  sred[3 * 256 + w * 64 + lane] = r3;
  __syncthreads();
  if (w == 0 && valid) {
    float o0 = sred[lane]       + sred[64 + lane]       + sred[128 + lane]       + sred[192 + lane];
    float o1 = sred[256 + lane] + sred[256 + 64 + lane] + sred[256 + 128 + lane] + sred[256 + 192 + lane];
    float o2 = sred[512 + lane] + sred[512 + 64 + lane] + sred[512 + 128 + lane] + sred[512 + 192 + lane];
    float o3 = sred[768 + lane] + sred[768 + 64 + lane] + sred[768 + 128 + lane] + sred[768 + 192 + lane];
    float bs = ws[O_BSUM + L];
    float* procL = ws + O_PROC + PROCB_[L];
    int px0 = p4 * 4;
#define BORDFIX(oj, jj) do { int px = px0 + (jj), y = px / D, x = px - y * D;        \
      bool inr = ((unsigned)(x - 1) < (unsigned)(D - 2)) &&                          \
                 ((unsigned)(y - 1) < (unsigned)(D - 2));                            \
      if (!inr) oj = bs; } while (0)
    if constexpr (NCH == 1) {
      BORDFIX(o0,0); BORDFIX(o1,1); BORDFIX(o2,2); BORDFIX(o3,3);
      ((float4*)procL)[p4] = make_float4(o0, o1, o2, o3);
    } else {
#define BORDADD(oj, jj) do { int px = px0 + (jj), y = px / D, x = px - y * D;        \
      bool inr = ((unsigned)(x - 1) < (unsigned)(D - 2)) &&                          \
                 ((unsigned)(y - 1) < (unsigned)(D - 2));                            \
      if (inr) atomicAdd(procL + px, oj);                                            \
      else if (chunk == 0) procL[px] = bs; } while (0)
      BORDADD(o0,0); BORDADD(o1,1); BORDADD(o2,2); BORDADD(o3,3);
#undef BORDADD
    }
#undef BORDFIX
  }
}
__global__ __launch_bounds__(TPB, 4) void kC(P p) {
  __shared__ float slut[1024];
  __shared__ float sred[1024];
  int b = blockIdx.x;
  if      (b <  900) bodyC<0>(b,        p.in[0], p.ws, slut, sred);
  else if (b < 1350) bodyC<1>(b -  900, p.in[1], p.ws, slut, sred);
  else if (b < 1578) bodyC<2>(b - 1350, p.in[2], p.ws, slut, sred);
  else if (b < 1698) bodyC<3>(b - 1578, p.in[3], p.ws, slut, sred);
  else               bodyC<4>(b - 1698, p.in[4], p.ws, slut, sred);
}

// ---------------- pass D: per-layer proc min/max ----------------
template <int L>
__device__ void bodyD(int chunk, float* ws) {
  constexpr int HW = DIMS_[L] * DIMS_[L];
  const float* pr = ws + O_PROC + PROCB_[L];
  int t = threadIdx.x;
  float mn = INFINITY, mx = 0.0f;   // proc >= 0
  #pragma unroll
  for (int i = 0; i < 16; i++) {
    int idx = chunk * 4096 + i * TPB + t;
    if (idx < HW) { float v = pr[idx]; mn = fminf(mn, v); mx = fmaxf(mx, v); }
  }
  for (int o = 32; o; o >>= 1) { mn = fminf(mn, __shfl_down(mn, o)); mx = fmaxf(mx, __shfl_down(mx, o)); }
  __shared__ float smn[4], smx[4];
  int w = t >> 6;
  if ((t & 63) == 0) { smn[w] = mn; smx[w] = mx; }
  __syncthreads();
  if (t == 0) {
    mn = fminf(fminf(smn[0], smn[1]), fminf(smn[2], smn[3]));
    mx = fmaxf(fmaxf(smx[0], smx[1]), fmaxf(smx[2], smx[3]));
    atomicMin((unsigned*)ws + O_PMIN + L, __float_as_uint(mn));
    atomicMax((unsigned*)ws + O_PMAX + L, __float_as_uint(mx));
  }
}
__global__ void kD(P p) {
  int b = blockIdx.x;
  if      (b < 57) bodyD<0>(b,      p.ws);
  else if (b < 72) bodyD<1>(b - 57, p.ws);
  else if (b < 76) bodyD<2>(b - 72, p.ws);
  else if (b < 77) bodyD<3>(b - 76, p.ws);
  else             bodyD<4>(b - 77, p.ws);
}

// ---- pass F: normalize(proc,0,1) + threshold + jax bilinear resize, fused layer stats ----
template <int L>
__device__ float bodyF(int px, float* ws) {
  constexpr int D = DIMS_[L];
  constexpr float INV = (float)D / 240.0f;
  constexpr float KS = (INV > 1.0f) ? INV : 1.0f;
  int oy = px / 240, ox = px - oy * 240;
  float mnv = __uint_as_float(((unsigned*)ws)[O_PMIN + L]);
  float mxv = __uint_as_float(((unsigned*)ws)[O_PMAX + L]);
  float pr = mxv - mnv;
  const float* procL = ws + O_PROC + PROCB_[L];
  float sfy = ((float)oy + 0.5f) * INV - 0.5f;
  float sfx = ((float)ox + 0.5f) * INV - 0.5f;
  int y0 = (int)ceilf(sfy - KS);  if (y0 < 0) y0 = 0;
  int y1 = (int)floorf(sfy + KS); if (y1 > D - 1) y1 = D - 1;
  int x0 = (int)ceilf(sfx - KS);  if (x0 < 0) x0 = 0;
  int x1 = (int)floorf(sfx + KS); if (x1 > D - 1) x1 = D - 1;
  float wsx = 0.0f;
  for (int jx = x0; jx <= x1; jx++) wsx += fmaxf(1.0f - fabsf(sfx - (float)jx) / KS, 0.0f);
  float acc = 0.0f, wsy = 0.0f;
  for (int jy = y0; jy <= y1; jy++) {
    float wy = fmaxf(1.0f - fabsf(sfy - (float)jy) / KS, 0.0f);
    wsy += wy;
    if (wy > 0.0f) {
      const float* row = procL + jy * D;
      float rs = 0.0f;
      for (int jx = x0; jx <= x1; jx++) {
        float wx = fmaxf(1.0f - fabsf(sfx - (float)jx) / KS, 0.0f);
        if (wx > 0.0f) {
          float v = row[jx];
          float tv = (pr == 0.0f) ? 0.0f : ((v - mnv) / pr);
          tv = (tv < 0.2f) ? 0.0f : tv;
          rs += wx * tv;
        }
      }
      acc += wy * rs;
    }
  }
  return acc / (wsy * wsx);
}
__global__ void kF(P p) {
  float* ws = p.ws;
  int b = blockIdx.x, l = b / 225;
  int px = (b - l * 225) * TPB + threadIdx.x;
  float res;
  switch (l) {
    case 0: res = bodyF<0>(px, ws); break;
    case 1: res = bodyF<1>(px, ws); break;
    case 2: res = bodyF<2>(px, ws); break;
    case 3: res = bodyF<3>(px, ws); break;
    default: res = bodyF<4>(px, ws); break;
  }
  ws[O_RESZ + l * 57600 + px] = res;
  float mn = res, mx = res, s = res;
  for (int o = 32; o; o >>= 1) {
    mn = fminf(mn, __shfl_down(mn, o));
    mx = fmaxf(mx, __shfl_down(mx, o));
    s += __shfl_down(s, o);
  }
  __shared__ float smn[4], smx[4], ssm[4];
  int t = threadIdx.x, w = t >> 6;
  if ((t & 63) == 0) { smn[w] = mn; smx[w] = mx; ssm[w] = s; }
  __syncthreads();
  if (t == 0) {
    mn = fminf(fminf(smn[0], smn[1]), fminf(smn[2], smn[3]));
    mx = fmaxf(fmaxf(smx[0], smx[1]), fmaxf(smx[2], smx[3]));
    s = ssm[0] + ssm[1] + ssm[2] + ssm[3];
    atomicMin((unsigned*)ws + O_S3MIN + l, __float_as_uint(mn));
    atomicMax((unsigned*)ws + O_S3MAX + l, __float_as_uint(mx));
    atomicAdd(ws + O_S3SUM + l, s);
  }
}

// ---------------- G2: final ponder + normalize(.,0,256), groups + sum ----------------
__global__ void kG2(P p, float* __restrict__ out) {
  float* ws = p.ws;
  int px = blockIdx.x * TPB + threadIdx.x;   // 225*256 == 57600
  float sum = 0.0f;
  #pragma unroll
  for (int l = 0; l < 5; l++) {
    float v = ws[O_RESZ + l * 57600 + px];
    float mn3 = __uint_as_float(((unsigned*)ws)[O_S3MIN + l]);
    float mx3 = __uint_as_float(((unsigned*)ws)[O_S3MAX + l]);
    float mean3 = ws[O_S3SUM + l] / 57600.0f;
    float r3 = mx3 - mn3;
    float ov;
    if (r3 == 0.0f) ov = 0.0f;
    else {
      float w3 = mx3 - mean3; w3 *= w3;
      if (w3 == 0.0f) ov = 0.0f;
      else ov = ((v - mn3) / r3) * w3 / w3 * 256.0f;
    }
    out[57600 + px * 5 + l] = ov;
    sum += ov;
  }
  out[px] = sum;
}

extern "C" void kernel_launch(void* const* d_in, const int* in_sizes, int n_in,
                              void* d_out, int out_size, void* d_ws, size_t ws_size,
                              hipStream_t stream) {
  (void)in_sizes; (void)n_in; (void)out_size; (void)ws_size;
  P p;
  for (int i = 0; i < 5; i++) p.in[i] = (const float*)d_in[i];
  p.ws = (float*)d_ws;
  float* out = (float*)d_out;

  k_init<<<(N_INIT + TPB - 1) / TPB, TPB, 0, stream>>>(p.ws);
  kA  <<<2752, TPB, 0, stream>>>(p);
  kB  <<<2752 + TOTCH, TPB, 0, stream>>>(p);   // +1472 border-fix blocks
  kS  <<<6,    TPB, 0, stream>>>(p);
  kC  <<<1730, TPB, 0, stream>>>(p);
  kD  <<<78,   TPB, 0, stream>>>(p);
  kF  <<<1125, TPB, 0, stream>>>(p);
  kG2 <<<225,  TPB, 0, stream>>>(p, out);
}

// Round 6
// 285.935 us; speedup vs baseline: 1.2576x; 1.0327x over previous
//
#include <hip/hip_runtime.h>
#include <math.h>

#define TPB 256

typedef float f4 __attribute__((ext_vector_type(4)));

// ---------------- layer geometry ----------------
constexpr int DIMS_[5]  = {480, 240, 120, 60, 30};
constexpr int CHS_ [5]  = {64, 128, 256, 512, 512};
constexpr int CHB_ [5]  = {0, 64, 192, 448, 960};
constexpr int TOTCH     = 1472;
constexpr int PROCB_[5] = {0, 230400, 288000, 302400, 306000};
constexpr int PROCTOT   = 306900;

// ---------------- ws layout (4-byte words) ----------------
constexpr int O_CHMIN = 0;                  // f32 [1472]
constexpr int O_CHMAX = 1472;               // f32 [1472]
constexpr int O_HIST  = 2944;               // u32 [1472*6]
constexpr int O_GCNT  = 11776;              // u32 [1472*6]
constexpr int O_CLUT  = 20608;              // f32 [1472*16]: unused[5], gthr[5], lut[6]
constexpr int O_BSUM  = O_CLUT + 16 * 1472; // 44160: f32 [5]
constexpr int O_PMIN  = O_BSUM + 5;         // u32 [5]
constexpr int O_PMAX  = O_PMIN + 5;         // u32 [5]
constexpr int O_S3MIN = O_PMAX + 5;         // u32 [5]
constexpr int O_S3MAX = O_S3MIN + 5;        // u32 [5]
constexpr int O_S3SUM = O_S3MAX + 5;        // f32 [5]
constexpr int O_PROC  = 44192;              // f32 [306900] (zero-init; chunked layers atomicAdd)
constexpr int O_RESZ  = O_PROC + PROCTOT;   // f32 [5*57600]
constexpr int N_INIT  = O_PROC + PROCTOT;   // init range

struct P {
  const float* in[5];
  float* ws;
};

// ---- asm load pipeline primitives ----
// LOAD4: 4 async global_load_dwordx4. The dest VGPRs are NOT valid until the
// matching tied wait retires.
#define LOAD4(d0,d1,d2,d3,p0,p1,p2,p3)                                               \
  asm volatile("global_load_dwordx4 %0, %4, off\n\t"                                 \
               "global_load_dwordx4 %1, %5, off\n\t"                                 \
               "global_load_dwordx4 %2, %6, off\n\t"                                 \
               "global_load_dwordx4 %3, %7, off"                                     \
               : "=&v"(d0), "=&v"(d1), "=&v"(d2), "=&v"(d3)                          \
               : "v"(p0), "v"(p1), "v"(p2), "v"(p3)                                  \
               : "memory")

// WAITV4: counted vmcnt wait with the 4 about-to-be-consumed quads TIED
// through the asm ("+v"). Round-5 lesson: a bare "memory"-clobber wait does
// not stop RA from copying/spilling a still-pending load dest between the
// load and the wait (async reg write) -> garbage. Tying makes the only
// consumable value the post-wait definition. sched_barrier stops the
// post-RA scheduler hoisting register-only consumers (rule-18 hazard).
#define WAITV4(n, a, b, c, d) do {                                                   \
    asm volatile("s_waitcnt vmcnt(" #n ")"                                           \
                 : "+v"(a), "+v"(b), "+v"(c), "+v"(d) :: "memory");                  \
    __builtin_amdgcn_sched_barrier(0);                                               \
  } while (0)

// ---------------- threshold helpers (same formulas everywhere) ----------------
// hb >= k+1  <=>  v >= mn + rng*(k+1)/6       (k = 0..4)
// gb >= k+1  <=>  v >= mn + rng*(k+2)/1536    (k = 0..4)
__device__ __forceinline__ void mk_hthr(float mn, float rng, float* th) {
  if (rng == 0.0f) { th[0]=th[1]=th[2]=th[3]=th[4]=INFINITY; return; }
  th[0] = mn + rng * (1.0f / 6.0f); th[1] = mn + rng * (2.0f / 6.0f);
  th[2] = mn + rng * (3.0f / 6.0f); th[3] = mn + rng * (4.0f / 6.0f);
  th[4] = mn + rng * (5.0f / 6.0f);
}
__device__ __forceinline__ void mk_gthr(float mn, float rng, float* tg) {
  if (rng == 0.0f) { tg[0]=tg[1]=tg[2]=tg[3]=tg[4]=INFINITY; return; }
  tg[0] = mn + rng * (2.0f / 1536.0f); tg[1] = mn + rng * (3.0f / 1536.0f);
  tg[2] = mn + rng * (4.0f / 1536.0f); tg[3] = mn + rng * (5.0f / 1536.0f);
  tg[4] = mn + rng * (6.0f / 1536.0f);
}

// ---------------- init ----------------
__global__ void k_init(float* ws) {
  int i = blockIdx.x * TPB + threadIdx.x;
  if (i >= N_INIT) return;
  unsigned v = 0u;
  if (i < O_CHMAX) v = 0x7F800000u;                       // chmin = +inf
  else if (i >= O_PMIN  && i < O_PMAX)  v = 0x7F800000u;  // pmin
  else if (i >= O_S3MIN && i < O_S3MAX) v = 0x7F800000u;  // s3min
  ((unsigned*)ws)[i] = v;
}

// ---------------- pass A: per-channel min/max of border-zeroed map (float4) ----------------
// r1-proven code (VGPR 24, no spill) — unchanged.
template <int L>
__device__ void bodyA(int local, const float* __restrict__ in, float* ws) {
  constexpr int D = DIMS_[L], HW = D * D, HW4 = HW / 4;
  constexpr int BPC = (HW4 + 4095) / 4096;
  constexpr int DQ = D / 4;
  int ch = local / BPC, chunk = local % BPC;
  int nvec = HW4 - chunk * 4096; if (nvec > 4096) nvec = 4096;
  const float4* pv = (const float4*)(in + (size_t)ch * HW) + (size_t)chunk * 4096;
  int t = threadIdx.x;
  float mn = INFINITY, mx = 0.0f;
  #pragma unroll 4
  for (int i = 0; i < 16; i++) {
    int vi = i * TPB + t;
    if (vi < nvec) {
      float4 v = pv[vi];
      float vv[4] = {v.x, v.y, v.z, v.w};
      int f4i = chunk * 4096 + vi;
      if constexpr (D % 4 == 0) {           // whole f4 on one row
        int y = f4i / DQ, xq = f4i - y * DQ;
        if (y == 0 || y == D - 1) { vv[0] = vv[1] = vv[2] = vv[3] = 0.0f; }
        else {
          if (xq == 0)      vv[0] = 0.0f;
          if (xq == DQ - 1) vv[3] = 0.0f;
        }
      } else {                              // D==30: f4 may straddle rows
        int e0 = f4i * 4;
        #pragma unroll
        for (int j = 0; j < 4; j++) {
          int e = e0 + j, y = e / D, x = e - y * D;
          bool inr = ((unsigned)(x - 1) < (unsigned)(D - 2)) && ((unsigned)(y - 1) < (unsigned)(D - 2));
          if (!inr) vv[j] = 0.0f;
        }
      }
      #pragma unroll
      for (int j = 0; j < 4; j++) { mn = fminf(mn, vv[j]); mx = fmaxf(mx, vv[j]); }
    }
  }
  for (int o = 32; o; o >>= 1) { mn = fminf(mn, __shfl_down(mn, o)); mx = fmaxf(mx, __shfl_down(mx, o)); }
  __shared__ float smn[4], smx[4];
  int w = t >> 6;
  if ((t & 63) == 0) { smn[w] = mn; smx[w] = mx; }
  __syncthreads();
  if (t == 0) {
    mn = fminf(fminf(smn[0], smn[1]), fminf(smn[2], smn[3]));
    mx = fmaxf(fmaxf(smx[0], smx[1]), fmaxf(smx[2], smx[3]));
    int g = CHB_[L] + ch;
    atomicMin((unsigned*)ws + O_CHMIN + g, __float_as_uint(mn));  // values >= 0
    atomicMax((unsigned*)ws + O_CHMAX + g, __float_as_uint(mx));
  }
}
__global__ void kA(P p) {
  int b = blockIdx.x;
  if      (b <  960) bodyA<0>(b,        p.in[0], p.ws);
  else if (b < 1472) bodyA<1>(b -  960, p.in[1], p.ws);
  else if (b < 1728) bodyA<2>(b - 1472, p.in[2], p.ws);
  else if (b < 2240) bodyA<3>(b - 1728, p.in[3], p.ws);
  else               bodyA<4>(b - 2240, p.in[4], p.ws);
}

// ---- pass B: per-lane counters; full chunks (L0/L1, 79% of bytes) use the
// tied-wait asm pipeline (8 loads in flight/wave); tails use r1's loop. ----
template <int L>
__device__ void bodyB(int local, const float* __restrict__ in, float* ws) {
  constexpr int D = DIMS_[L], HW = D * D, HW4 = HW / 4;
  constexpr int BPC = (HW4 + 4095) / 4096;
  constexpr int DQ = D / 4;
  int ch = local / BPC, chunk = local % BPC;
  int g = CHB_[L] + ch;
  float mn = ws[O_CHMIN + g], mx = ws[O_CHMAX + g], rng = mx - mn;
  float th[5], tg[5];
  mk_hthr(mn, rng, th);
  mk_gthr(mn, rng, tg);
  int nvec = HW4 - chunk * 4096; if (nvec > 4096) nvec = 4096;
  int t = threadIdx.x;
  unsigned c[10] = {0u,0u,0u,0u,0u,0u,0u,0u,0u,0u};  // c[0..4]=cH, c[5..9]=cG
  unsigned nval = 0u;
  auto cnt1 = [&](float x) {
    #pragma unroll
    for (int k = 0; k < 5; k++) { c[k] += (x >= th[k]); c[5 + k] += (x >= tg[k]); }
  };
  bool fullchunk = (nvec == 4096);
  if constexpr (HW4 >= 4096) {
    if (fullchunk) {     // only L0/L1 reach here -> D % 4 == 0 guaranteed
      const f4* q = (const f4*)(in + (size_t)ch * HW) + (size_t)chunk * 4096 + t;
      int base = chunk * 4096 + t;
      auto zbcnt = [&](f4 v, int ii) {
        int f4i = base + ii * TPB;
        int yy = f4i / DQ, xq = f4i - yy * DQ;
        if (yy == 0 || yy == D - 1) { v.x = 0.0f; v.y = 0.0f; v.z = 0.0f; v.w = 0.0f; }
        else {
          if (xq == 0)      v.x = 0.0f;
          if (xq == DQ - 1) v.w = 0.0f;
        }
        cnt1(v.x); cnt1(v.y); cnt1(v.z); cnt1(v.w);
      };
      f4 x0, x1, x2, x3, y0, y1, y2, y3;
      LOAD4(x0,x1,x2,x3, q,           q + TPB,     q + 2*TPB,  q + 3*TPB);
      LOAD4(y0,y1,y2,y3, q + 4*TPB,   q + 5*TPB,   q + 6*TPB,  q + 7*TPB);
      WAITV4(4, x0,x1,x2,x3);
      zbcnt(x0,0); zbcnt(x1,1); zbcnt(x2,2); zbcnt(x3,3);
      LOAD4(x0,x1,x2,x3, q + 8*TPB,   q + 9*TPB,   q + 10*TPB, q + 11*TPB);
      WAITV4(4, y0,y1,y2,y3);
      zbcnt(y0,4); zbcnt(y1,5); zbcnt(y2,6); zbcnt(y3,7);
      LOAD4(y0,y1,y2,y3, q + 12*TPB,  q + 13*TPB,  q + 14*TPB, q + 15*TPB);
      WAITV4(4, x0,x1,x2,x3);
      zbcnt(x0,8); zbcnt(x1,9); zbcnt(x2,10); zbcnt(x3,11);
      WAITV4(0, y0,y1,y2,y3);
      zbcnt(y0,12); zbcnt(y1,13); zbcnt(y2,14); zbcnt(y3,15);
      nval = 64u;
    }
  }
  if (!fullchunk || HW4 < 4096) {   // r1-proven tail path
    const float4* pv = (const float4*)(in + (size_t)ch * HW) + (size_t)chunk * 4096;
    #pragma unroll 4
    for (int i = 0; i < 16; i++) {
      int vi = i * TPB + t;
      if (vi < nvec) {
        float4 v = pv[vi];
        float vv[4] = {v.x, v.y, v.z, v.w};
        int f4i = chunk * 4096 + vi;
        if constexpr (D % 4 == 0) {
          int y = f4i / DQ, xq = f4i - y * DQ;
          if (y == 0 || y == D - 1) { vv[0] = vv[1] = vv[2] = vv[3] = 0.0f; }
          else {
            if (xq == 0)      vv[0] = 0.0f;
            if (xq == DQ - 1) vv[3] = 0.0f;
          }
        } else {
          int e0 = f4i * 4;
          #pragma unroll
          for (int j = 0; j < 4; j++) {
            int e = e0 + j, y = e / D, x = e - y * D;
            bool inr = ((unsigned)(x - 1) < (unsigned)(D - 2)) && ((unsigned)(y - 1) < (unsigned)(D - 2));
            if (!inr) vv[j] = 0.0f;
          }
        }
        nval += 4u;
        cnt1(vv[0]); cnt1(vv[1]); cnt1(vv[2]); cnt1(vv[3]);
      }
    }
  }
  #pragma unroll
  for (int k = 0; k < 10; k++)
    for (int o = 32; o; o >>= 1) c[k] += __shfl_down(c[k], o);
  for (int o = 32; o; o >>= 1) nval += __shfl_down(nval, o);
  if ((t & 63) == 0) {
    unsigned* H = (unsigned*)ws + O_HIST + g * 6;
    unsigned* G = (unsigned*)ws + O_GCNT + g * 6;
    atomicAdd(H + 0, nval - c[0]); atomicAdd(H + 1, c[0] - c[1]);
    atomicAdd(H + 2, c[1] - c[2]); atomicAdd(H + 3, c[2] - c[3]);
    atomicAdd(H + 4, c[3] - c[4]); atomicAdd(H + 5, c[4]);
    atomicAdd(G + 0, nval - c[5]); atomicAdd(G + 1, c[5] - c[6]);
    atomicAdd(G + 2, c[6] - c[7]); atomicAdd(G + 3, c[7] - c[8]);
    atomicAdd(G + 4, c[8] - c[9]); atomicAdd(G + 5, c[9]);
  }
}
__global__ __launch_bounds__(TPB, 4) void kB(P p) {
  int b = blockIdx.x;
  if      (b <  960) bodyB<0>(b,        p.in[0], p.ws);
  else if (b < 1472) bodyB<1>(b -  960, p.in[1], p.ws);
  else if (b < 1728) bodyB<2>(b - 1472, p.in[2], p.ws);
  else if (b < 2240) bodyB<3>(b - 1728, p.in[3], p.ws);
  else               bodyB<4>(b - 2240, p.in[4], p.ws);
}

// ---------------- kernel S: per-channel LUT construction (r1-proven) ----------------
__global__ void kS(P p) {
  int ch = blockIdx.x * TPB + threadIdx.x;
  if (ch >= TOTCH) return;
  float* ws = p.ws;
  int l = (ch < 64) ? 0 : (ch < 192) ? 1 : (ch < 448) ? 2 : (ch < 960) ? 3 : 4;
  int D = DIMS_[l];
  int HW = D * D;
  int c0 = ch - CHB_[l];
  unsigned hc[6], gc[6];
  unsigned* H = (unsigned*)ws + O_HIST + ch * 6;
  unsigned* G = (unsigned*)ws + O_GCNT + ch * 6;
  #pragma unroll
  for (int k = 0; k < 6; k++) { hc[k] = H[k]; gc[k] = G[k]; }
  float HWf = (float)HW;
  float nh[6];
  #pragma unroll
  for (int k = 0; k < 6; k++) nh[k] = -logf((float)hc[k] / HWf + 1e-4f);
  float dmn = INFINITY, dmx = -INFINITY;
  #pragma unroll
  for (int k = 0; k < 6; k++) if (gc[k]) { dmn = fminf(dmn, nh[k]); dmx = fmaxf(dmx, nh[k]); }
  float dr = dmx - dmn;
  float dstn[6];
  #pragma unroll
  for (int k = 0; k < 6; k++) dstn[k] = (dr == 0.0f) ? 0.0f : ((nh[k] - dmn) / dr);
  float maxv = (dr == 0.0f) ? 0.0f : 1.0f;
  double s1 = 0.0;
  #pragma unroll
  for (int k = 0; k < 6; k++) s1 += (double)gc[k] * (double)dstn[k];
  float mean1 = (float)(s1 / (double)HW);
  float w1 = maxv - mean1; w1 *= w1;
  float lut1[6];
  #pragma unroll
  for (int k = 0; k < 6; k++) lut1[k] = dstn[k] * w1;
  float mnc = ws[O_CHMIN + ch], mxc = ws[O_CHMAX + ch];
  float tg[5];
  mk_gthr(mnc, mxc - mnc, tg);
  int gb = (0.0f >= tg[0]) + (0.0f >= tg[1]) + (0.0f >= tg[2]) + (0.0f >= tg[3]) + (0.0f >= tg[4]);
  unsigned bcnt = (unsigned)(4 * D - 4);
  float lmn, lmx;
  double s2 = 0.0;
  if (c0 == 0) {   // channel 0 keeps its border
    lmn = INFINITY; lmx = -INFINITY;
    #pragma unroll
    for (int k = 0; k < 6; k++) if (gc[k]) {
      lmn = fminf(lmn, lut1[k]); lmx = fmaxf(lmx, lut1[k]);
      s2 += (double)gc[k] * (double)lut1[k];
    }
  } else {
    lmn = 0.0f; lmx = 0.0f;   // border zeros present
    #pragma unroll
    for (int k = 0; k < 6; k++) {
      unsigned ic = gc[k] - ((k == gb) ? bcnt : 0u);
      if (ic) {
        lmn = fminf(lmn, lut1[k]); lmx = fmaxf(lmx, lut1[k]);
        s2 += (double)ic * (double)lut1[k];
      }
    }
  }
  float mean2 = (float)(s2 / (double)HW);
  float w2 = lmx - mean2; w2 *= w2;
  float r2 = lmx - lmn;
  float lout[6];
  #pragma unroll
  for (int k = 0; k < 6; k++) lout[k] = (r2 == 0.0f) ? 0.0f : (((lut1[k] - lmn) / r2) * w2);
  float* T = ws + O_CLUT + (size_t)ch * 16;
  #pragma unroll
  for (int k = 0; k < 5; k++) T[5 + k] = tg[k];
  #pragma unroll
  for (int k = 0; k < 6; k++) T[10 + k] = lout[k];
  float bc = (c0 == 0) ? lout[gb] : ((r2 == 0.0f) ? 0.0f : (((0.0f - lmn) / r2) * w2));
  atomicAdd(ws + O_BSUM + l, bc);
}

// ---- pass C: proc = sum_c LUT[gb_c(v)] (r1-proven) ----
template <int L>
__device__ void bodyC(int local, const float* __restrict__ in, float* ws,
                      float* slut, float* sred) {
  constexpr int D = DIMS_[L], HW = D * D, HW4 = HW / 4, C = CHS_[L];
  constexpr int NT  = (HW4 + 63) / 64;   // tiles per layer
  constexpr int NCH = C / 64;            // channel chunks
  int tile = local % NT, chunk = local / NT;
  int cbase = CHB_[L] + chunk * 64;
  int t = threadIdx.x, lane = t & 63, w = t >> 6;
  const float* gl = ws + O_CLUT + (size_t)cbase * 16;
  for (int i = t; i < 1024; i += TPB) slut[i] = gl[i];
  __syncthreads();
  int p4 = tile * 64 + lane;
  bool valid = p4 < HW4;
  float a0 = 0.0f, a1 = 0.0f, a2 = 0.0f, a3 = 0.0f;
  if (valid) {
    const float4* bp = (const float4*)in + (size_t)(chunk * 64 + w * 16) * HW4 + p4;
    const float* su = slut + (w * 16) * 16;
    #pragma unroll 4
    for (int c = 0; c < 16; c++) {
      float4 v = bp[(size_t)c * HW4];
      const float* cl = su + c * 16 + 5;
      float g0 = cl[0], g1 = cl[1], g2 = cl[2], g3 = cl[3], g4 = cl[4];
      float l0 = cl[5], l1 = cl[6], l2 = cl[7], l3 = cl[8], l4 = cl[9], l5 = cl[10];
      float s;
      s = (v.x >= g0) ? l1 : l0; s = (v.x >= g1) ? l2 : s; s = (v.x >= g2) ? l3 : s;
      s = (v.x >= g3) ? l4 : s;  s = (v.x >= g4) ? l5 : s; a0 += s;
      s = (v.y >= g0) ? l1 : l0; s = (v.y >= g1) ? l2 : s; s = (v.y >= g2) ? l3 : s;
      s = (v.y >= g3) ? l4 : s;  s = (v.y >= g4) ? l5 : s; a1 += s;
      s = (v.z >= g0) ? l1 : l0; s = (v.z >= g1) ? l2 : s; s = (v.z >= g2) ? l3 : s;
      s = (v.z >= g3) ? l4 : s;  s = (v.z >= g4) ? l5 : s; a2 += s;
      s = (v.w >= g0) ? l1 : l0; s = (v.w >= g1) ? l2 : s; s = (v.w >= g2) ? l3 : s;
      s = (v.w >= g3) ? l4 : s;  s = (v.w >= g4) ? l5 : s; a3 += s;
    }
  }
  sred[0 * 256 + w * 64 + lane] = a0;
  sred[1 * 256 + w * 64 + lane] = a1;
  sred[2 * 256 + w * 64 + lane] = a2;
  sred[3 * 256 + w * 64 + lane] = a3;
  __syncthreads();
  if (w == 0 && valid) {
    float o[4];
    #pragma unroll
    for (int j = 0; j < 4; j++)
      o[j] = sred[j * 256 + lane] + sred[j * 256 + 64 + lane] +
             sred[j * 256 + 128 + lane] + sred[j * 256 + 192 + lane];
    float bs = ws[O_BSUM + L];
    float* procL = ws + O_PROC + PROCB_[L];
    int px0 = p4 * 4;
    if constexpr (NCH == 1) {
      #pragma unroll
      for (int j = 0; j < 4; j++) {
        int px = px0 + j, y = px / D, x = px - y * D;
        bool inr = ((unsigned)(x - 1) < (unsigned)(D - 2)) && ((unsigned)(y - 1) < (unsigned)(D - 2));
        if (!inr) o[j] = bs;
      }
      ((float4*)procL)[p4] = make_float4(o[0], o[1], o[2], o[3]);
    } else {
      #pragma unroll
      for (int j = 0; j < 4; j++) {
        int px = px0 + j, y = px / D, x = px - y * D;
        bool inr = ((unsigned)(x - 1) < (unsigned)(D - 2)) && ((unsigned)(y - 1) < (unsigned)(D - 2));
        if (inr) atomicAdd(procL + px, o[j]);
        else if (chunk == 0) procL[px] = bs;   // sole writer of border pixels
      }
    }
  }
}
__global__ __launch_bounds__(TPB) void kC(P p) {
  __shared__ float slut[1024];
  __shared__ float sred[1024];
  int b = blockIdx.x;
  if      (b <  900) bodyC<0>(b,        p.in[0], p.ws, slut, sred);
  else if (b < 1350) bodyC<1>(b -  900, p.in[1], p.ws, slut, sred);
  else if (b < 1578) bodyC<2>(b - 1350, p.in[2], p.ws, slut, sred);
  else if (b < 1698) bodyC<3>(b - 1578, p.in[3], p.ws, slut, sred);
  else               bodyC<4>(b - 1698, p.in[4], p.ws, slut, sred);
}

// ---------------- pass D: per-layer proc min/max ----------------
template <int L>
__device__ void bodyD(int chunk, float* ws) {
  constexpr int HW = DIMS_[L] * DIMS_[L];
  const float* pr = ws + O_PROC + PROCB_[L];
  int t = threadIdx.x;
  float mn = INFINITY, mx = 0.0f;   // proc >= 0
  #pragma unroll
  for (int i = 0; i < 16; i++) {
    int idx = chunk * 4096 + i * TPB + t;
    if (idx < HW) { float v = pr[idx]; mn = fminf(mn, v); mx = fmaxf(mx, v); }
  }
  for (int o = 32; o; o >>= 1) { mn = fminf(mn, __shfl_down(mn, o)); mx = fmaxf(mx, __shfl_down(mx, o)); }
  __shared__ float smn[4], smx[4];
  int w = t >> 6;
  if ((t & 63) == 0) { smn[w] = mn; smx[w] = mx; }
  __syncthreads();
  if (t == 0) {
    mn = fminf(fminf(smn[0], smn[1]), fminf(smn[2], smn[3]));
    mx = fmaxf(fmaxf(smx[0], smx[1]), fmaxf(smx[2], smx[3]));
    atomicMin((unsigned*)ws + O_PMIN + L, __float_as_uint(mn));
    atomicMax((unsigned*)ws + O_PMAX + L, __float_as_uint(mx));
  }
}
__global__ void kD(P p) {
  int b = blockIdx.x;
  if      (b < 57) bodyD<0>(b,      p.ws);
  else if (b < 72) bodyD<1>(b - 57, p.ws);
  else if (b < 76) bodyD<2>(b - 72, p.ws);
  else if (b < 77) bodyD<3>(b - 76, p.ws);
  else             bodyD<4>(b - 77, p.ws);
}

// ---- pass F: normalize(proc,0,1) + threshold + jax bilinear resize, fused layer stats ----
template <int L>
__device__ float bodyF(int px, float* ws) {
  constexpr int D = DIMS_[L];
  constexpr float INV = (float)D / 240.0f;
  constexpr float KS = (INV > 1.0f) ? INV : 1.0f;
  int oy = px / 240, ox = px - oy * 240;
  float mnv = __uint_as_float(((unsigned*)ws)[O_PMIN + L]);
  float mxv = __uint_as_float(((unsigned*)ws)[O_PMAX + L]);
  float pr = mxv - mnv;
  const float* procL = ws + O_PROC + PROCB_[L];
  float sfy = ((float)oy + 0.5f) * INV - 0.5f;
  float sfx = ((float)ox + 0.5f) * INV - 0.5f;
  int y0 = (int)ceilf(sfy - KS);  if (y0 < 0) y0 = 0;
  int y1 = (int)floorf(sfy + KS); if (y1 > D - 1) y1 = D - 1;
  int x0 = (int)ceilf(sfx - KS);  if (x0 < 0) x0 = 0;
  int x1 = (int)floorf(sfx + KS); if (x1 > D - 1) x1 = D - 1;
  float wsx = 0.0f;
  for (int jx = x0; jx <= x1; jx++) wsx += fmaxf(1.0f - fabsf(sfx - (float)jx) / KS, 0.0f);
  float acc = 0.0f, wsy = 0.0f;
  for (int jy = y0; jy <= y1; jy++) {
    float wy = fmaxf(1.0f - fabsf(sfy - (float)jy) / KS, 0.0f);
    wsy += wy;
    if (wy > 0.0f) {
      const float* row = procL + jy * D;
      float rs = 0.0f;
      for (int jx = x0; jx <= x1; jx++) {
        float wx = fmaxf(1.0f - fabsf(sfx - (float)jx) / KS, 0.0f);
        if (wx > 0.0f) {
          float v = row[jx];
          float tv = (pr == 0.0f) ? 0.0f : ((v - mnv) / pr);
          tv = (tv < 0.2f) ? 0.0f : tv;
          rs += wx * tv;
        }
      }
      acc += wy * rs;
    }
  }
  return acc / (wsy * wsx);
}
__global__ void kF(P p) {
  float* ws = p.ws;
  int b = blockIdx.x, l = b / 225;
  int px = (b - l * 225) * TPB + threadIdx.x;
  float res;
  switch (l) {
    case 0: res = bodyF<0>(px, ws); break;
    case 1: res = bodyF<1>(px, ws); break;
    case 2: res = bodyF<2>(px, ws); break;
    case 3: res = bodyF<3>(px, ws); break;
    default: res = bodyF<4>(px, ws); break;
  }
  ws[O_RESZ + l * 57600 + px] = res;
  float mn = res, mx = res, s = res;
  for (int o = 32; o; o >>= 1) {
    mn = fminf(mn, __shfl_down(mn, o));
    mx = fmaxf(mx, __shfl_down(mx, o));
    s += __shfl_down(s, o);
  }
  __shared__ float smn[4], smx[4], ssm[4];
  int t = threadIdx.x, w = t >> 6;
  if ((t & 63) == 0) { smn[w] = mn; smx[w] = mx; ssm[w] = s; }
  __syncthreads();
  if (t == 0) {
    mn = fminf(fminf(smn[0], smn[1]), fminf(smn[2], smn[3]));
    mx = fmaxf(fmaxf(smx[0], smx[1]), fmaxf(smx[2], smx[3]));
    s = ssm[0] + ssm[1] + ssm[2] + ssm[3];
    atomicMin((unsigned*)ws + O_S3MIN + l, __float_as_uint(mn));
    atomicMax((unsigned*)ws + O_S3MAX + l, __float_as_uint(mx));
    atomicAdd(ws + O_S3SUM + l, s);
  }
}

// ---------------- G2: final ponder + normalize(.,0,256), groups + sum ----------------
__global__ void kG2(P p, float* __restrict__ out) {
  float* ws = p.ws;
  int px = blockIdx.x * TPB + threadIdx.x;   // 225*256 == 57600
  float sum = 0.0f;
  #pragma unroll
  for (int l = 0; l < 5; l++) {
    float v = ws[O_RESZ + l * 57600 + px];
    float mn3 = __uint_as_float(((unsigned*)ws)[O_S3MIN + l]);
    float mx3 = __uint_as_float(((unsigned*)ws)[O_S3MAX + l]);
    float mean3 = ws[O_S3SUM + l] / 57600.0f;
    float r3 = mx3 - mn3;
    float ov;
    if (r3 == 0.0f) ov = 0.0f;
    else {
      float w3 = mx3 - mean3; w3 *= w3;
      if (w3 == 0.0f) ov = 0.0f;
      else ov = ((v - mn3) / r3) * w3 / w3 * 256.0f;
    }
    out[57600 + px * 5 + l] = ov;
    sum += ov;
  }
  out[px] = sum;
}

extern "C" void kernel_launch(void* const* d_in, const int* in_sizes, int n_in,
                              void* d_out, int out_size, void* d_ws, size_t ws_size,
                              hipStream_t stream) {
  (void)in_sizes; (void)n_in; (void)out_size; (void)ws_size;
  P p;
  for (int i = 0; i < 5; i++) p.in[i] = (const float*)d_in[i];
  p.ws = (float*)d_ws;
  float* out = (float*)d_out;

  k_init<<<(N_INIT + TPB - 1) / TPB, TPB, 0, stream>>>(p.ws);
  kA  <<<2752, TPB, 0, stream>>>(p);
  kB  <<<2752, TPB, 0, stream>>>(p);
  kS  <<<6,    TPB, 0, stream>>>(p);
  kC  <<<1730, TPB, 0, stream>>>(p);
  kD  <<<78,   TPB, 0, stream>>>(p);
  kF  <<<1125, TPB, 0, stream>>>(p);
  kG2 <<<225,  TPB, 0, stream>>>(p, out);
}